// Round 1
// baseline (2105.670 us; speedup 1.0000x reference)
//
#include <hip/hip_runtime.h>

// ---------------- degree / dinv ----------------

__global__ void deg_kernel(const int* __restrict__ dst, float* __restrict__ deg, int E) {
  int e = blockIdx.x * blockDim.x + threadIdx.x;
  if (e < E) atomicAdd(&deg[dst[e]], 1.0f);
}

__global__ void dinv_kernel(float* __restrict__ d, int N) {
  int i = blockIdx.x * blockDim.x + threadIdx.x;
  if (i < N) d[i] = 1.0f / sqrtf(d[i] + 1.0f);
}

// ---------------- tiled fp32 GEMM: O[N][COLS] = X[N][K] @ W[K][COLS] ----------------
// 256 threads, 4x4 micro-tile per thread, ROWS*COLS must equal 4096.

template <int ROWS, int COLS, int K>
__global__ __launch_bounds__(256) void gemm_kernel(const float* __restrict__ X,
                                                   const float* __restrict__ W,
                                                   float* __restrict__ O, int N) {
  __shared__ float xs[ROWS][K + 4];   // +4 pad keeps float4 alignment, breaks bank stride
  __shared__ float ws[K][COLS];
  const int t = threadIdx.x;
  const int row0 = blockIdx.x * ROWS;

  // stage W (fits entirely: K*COLS*4 <= 32KB)
  constexpr int WV = K * COLS / 4;
  for (int i = t; i < WV; i += 256) {
    float4 v = reinterpret_cast<const float4*>(W)[i];
    int base = i * 4;
    int k = base / COLS, c = base % COLS;
    ws[k][c] = v.x; ws[k][c + 1] = v.y; ws[k][c + 2] = v.z; ws[k][c + 3] = v.w;
  }
  // stage X tile (row-major), coalesced float4 loads
  constexpr int XV = ROWS * K / 4;
  for (int i = t; i < XV; i += 256) {
    int base = i * 4;
    int r = base / K, k = base % K;
    int row = row0 + r;
    float4 v = make_float4(0.f, 0.f, 0.f, 0.f);
    if (row < N) v = reinterpret_cast<const float4*>(X + (size_t)row * K)[k >> 2];
    *reinterpret_cast<float4*>(&xs[r][k]) = v;
  }
  __syncthreads();

  constexpr int TC = COLS / 4;
  const int tc = t % TC, tr = t / TC;
  const int c0 = tc * 4, r0 = tr * 4;
  float acc[4][4] = {{0.f}};

#pragma unroll 8
  for (int k = 0; k < K; ++k) {
    // a-reads: broadcast across the TC lanes sharing tr (scalar LDS reads)
    float a0 = xs[r0 + 0][k];
    float a1 = xs[r0 + 1][k];
    float a2 = xs[r0 + 2][k];
    float a3 = xs[r0 + 3][k];
    float4 b = *reinterpret_cast<const float4*>(&ws[k][c0]);
    acc[0][0] = fmaf(a0, b.x, acc[0][0]); acc[0][1] = fmaf(a0, b.y, acc[0][1]);
    acc[0][2] = fmaf(a0, b.z, acc[0][2]); acc[0][3] = fmaf(a0, b.w, acc[0][3]);
    acc[1][0] = fmaf(a1, b.x, acc[1][0]); acc[1][1] = fmaf(a1, b.y, acc[1][1]);
    acc[1][2] = fmaf(a1, b.z, acc[1][2]); acc[1][3] = fmaf(a1, b.w, acc[1][3]);
    acc[2][0] = fmaf(a2, b.x, acc[2][0]); acc[2][1] = fmaf(a2, b.y, acc[2][1]);
    acc[2][2] = fmaf(a2, b.z, acc[2][2]); acc[2][3] = fmaf(a2, b.w, acc[2][3]);
    acc[3][0] = fmaf(a3, b.x, acc[3][0]); acc[3][1] = fmaf(a3, b.y, acc[3][1]);
    acc[3][2] = fmaf(a3, b.z, acc[3][2]); acc[3][3] = fmaf(a3, b.w, acc[3][3]);
  }

#pragma unroll
  for (int i = 0; i < 4; ++i) {
    int row = row0 + r0 + i;
    if (row < N) {
      float4 o = make_float4(acc[i][0], acc[i][1], acc[i][2], acc[i][3]);
      *reinterpret_cast<float4*>(O + (size_t)row * COLS + c0) = o;
    }
  }
}

// ---------------- edge scatter: AGG[dst] += dinv[src]*dinv[dst] * H[src] ----------------
// FDIM/4 lanes per edge; float4 gather from the source row, 4 scalar atomics.

template <int FDIM>
__global__ void scatter_kernel(const int* __restrict__ src, const int* __restrict__ dst,
                               const float* __restrict__ dinv, const float* __restrict__ Hm,
                               float* __restrict__ AGG, int E) {
  constexpr int L = FDIM / 4;
  int id = blockIdx.x * blockDim.x + threadIdx.x;
  int e = id / L;
  int q = id % L;
  if (e >= E) return;
  int s = src[e], d = dst[e];
  float nrm = dinv[s] * dinv[d];
  float4 v = reinterpret_cast<const float4*>(Hm + (size_t)s * FDIM)[q];
  float* p = AGG + (size_t)d * FDIM + q * 4;
  atomicAdd(p + 0, v.x * nrm);
  atomicAdd(p + 1, v.y * nrm);
  atomicAdd(p + 2, v.z * nrm);
  atomicAdd(p + 3, v.w * nrm);
}

// ---------------- epilogues ----------------
// r = relu(agg + h*dinv^2 + b), FDIM=64 (16 float4 per row)
__global__ void fuse1_kernel(const float* __restrict__ agg, const float* __restrict__ h,
                             const float* __restrict__ dinv, const float* __restrict__ b,
                             float* __restrict__ r, int N) {
  int id = blockIdx.x * blockDim.x + threadIdx.x;
  if (id >= N * 16) return;
  int row = id >> 4, q = id & 15;
  float di = dinv[row];
  float d2 = di * di;
  float4 a = reinterpret_cast<const float4*>(agg)[id];
  float4 hv = reinterpret_cast<const float4*>(h)[id];
  float4 bv = reinterpret_cast<const float4*>(b)[q];
  float4 o;
  o.x = fmaxf(fmaf(hv.x, d2, a.x) + bv.x, 0.f);
  o.y = fmaxf(fmaf(hv.y, d2, a.y) + bv.y, 0.f);
  o.z = fmaxf(fmaf(hv.z, d2, a.z) + bv.z, 0.f);
  o.w = fmaxf(fmaf(hv.w, d2, a.w) + bv.w, 0.f);
  reinterpret_cast<float4*>(r)[id] = o;
}

// out += h*dinv^2 + b, FDIM=32 (8 float4 per row), no relu
__global__ void fuse2_kernel(float* __restrict__ out, const float* __restrict__ h,
                             const float* __restrict__ dinv, const float* __restrict__ b,
                             int N) {
  int id = blockIdx.x * blockDim.x + threadIdx.x;
  if (id >= N * 8) return;
  int row = id >> 3, q = id & 7;
  float di = dinv[row];
  float d2 = di * di;
  float4 a = reinterpret_cast<float4*>(out)[id];
  float4 hv = reinterpret_cast<const float4*>(h)[id];
  float4 bv = reinterpret_cast<const float4*>(b)[q];
  a.x += fmaf(hv.x, d2, bv.x);
  a.y += fmaf(hv.y, d2, bv.y);
  a.z += fmaf(hv.z, d2, bv.z);
  a.w += fmaf(hv.w, d2, bv.w);
  reinterpret_cast<float4*>(out)[id] = a;
}

// ---------------- launch ----------------

extern "C" void kernel_launch(void* const* d_in, const int* in_sizes, int n_in,
                              void* d_out, int out_size, void* d_ws, size_t ws_size,
                              hipStream_t stream) {
  const float* x  = (const float*)d_in[0];
  const int*   ei = (const int*)d_in[1];
  const float* W1 = (const float*)d_in[2];
  const float* b1 = (const float*)d_in[3];
  const float* W2 = (const float*)d_in[4];
  const float* b2 = (const float*)d_in[5];
  float* out = (float*)d_out;

  const int H = in_sizes[3];            // 64
  const int C = in_sizes[5];            // 32
  const int F = in_sizes[2] / H;        // 128
  const int N = in_sizes[0] / F;        // 100000
  const int E = in_sizes[1] / 2;        // 1600000
  const int* src = ei;
  const int* dst = ei + E;

  // workspace layout (floats): dinv[N] | h1[N*64] | buf1[N*64] | h2[N*32]
  float* ws = (float*)d_ws;
  size_t o = 0;
  float* dinv = ws + o; o += ((size_t)N + 15) & ~(size_t)15;
  float* h1   = ws + o; o += (size_t)N * 64;
  float* buf1 = ws + o; o += (size_t)N * 64;  // agg1, then relu output in-place
  float* h2   = ws + o;

  hipMemsetAsync(dinv, 0, (size_t)N * 4, stream);
  hipMemsetAsync(buf1, 0, (size_t)N * 64 * 4, stream);
  hipMemsetAsync(out,  0, (size_t)N * 32 * 4, stream);

  // degrees (with self-loop via +1 in dinv kernel)
  deg_kernel<<<(E + 255) / 256, 256, 0, stream>>>(dst, dinv, E);
  dinv_kernel<<<(N + 255) / 256, 256, 0, stream>>>(dinv, N);

  // layer 1: h1 = x @ W1
  gemm_kernel<64, 64, 128><<<(N + 63) / 64, 256, 0, stream>>>(x, W1, h1, N);
  // agg1 += norm * h1[src]
  {
    long long threads = (long long)E * 16;
    int blocks = (int)((threads + 255) / 256);
    scatter_kernel<64><<<blocks, 256, 0, stream>>>(src, dst, dinv, h1, buf1, E);
  }
  // r1 = relu(agg1 + h1*dinv^2 + b1)  (in place over buf1)
  fuse1_kernel<<<(N * 16 + 255) / 256, 256, 0, stream>>>(buf1, h1, dinv, b1, buf1, N);

  // layer 2: h2 = r1 @ W2
  gemm_kernel<128, 32, 64><<<(N + 127) / 128, 256, 0, stream>>>(buf1, W2, h2, N);
  // out += norm * h2[src]
  {
    long long threads = (long long)E * 8;
    int blocks = (int)((threads + 255) / 256);
    scatter_kernel<32><<<blocks, 256, 0, stream>>>(src, dst, dinv, h2, out, E);
  }
  // out += h2*dinv^2 + b2
  fuse2_kernel<<<(N * 8 + 255) / 256, 256, 0, stream>>>(out, h2, dinv, b2, N);
}

// Round 2
// 475.238 us; speedup vs baseline: 4.4308x; 4.4308x over previous
//
#include <hip/hip_runtime.h>

// ================= CSR build =================

__global__ void degi_kernel(const int* __restrict__ dst, int* __restrict__ deg, int E) {
  int e = blockIdx.x * blockDim.x + threadIdx.x;
  if (e < E) atomicAdd(&deg[dst[e]], 1);
}

// Pass A: per-1024-chunk inclusive scan -> rowptr[1+i]; chunk sums -> bsum
__global__ __launch_bounds__(256) void scanA_kernel(const int* __restrict__ deg,
                                                    int* __restrict__ incl1,  // rowptr+1
                                                    int* __restrict__ bsum, int N) {
  __shared__ int sdata[256];
  const int t = threadIdx.x;
  const int base = blockIdx.x * 1024 + t * 4;
  int v[4];
  int s = 0;
#pragma unroll
  for (int j = 0; j < 4; ++j) {
    v[j] = (base + j < N) ? deg[base + j] : 0;
    s += v[j];
  }
  sdata[t] = s;
  __syncthreads();
  for (int off = 1; off < 256; off <<= 1) {
    int x = 0;
    if (t >= off) x = sdata[t - off];
    __syncthreads();
    if (t >= off) sdata[t] += x;
    __syncthreads();
  }
  int run = (t > 0) ? sdata[t - 1] : 0;
#pragma unroll
  for (int j = 0; j < 4; ++j) {
    run += v[j];
    if (base + j < N) incl1[base + j] = run;
  }
  if (t == 255) bsum[blockIdx.x] = sdata[255];
}

// Pass B: single block, exclusive scan of up to 256 chunk sums -> boff
__global__ __launch_bounds__(256) void scanB_kernel(const int* __restrict__ bsum,
                                                    int* __restrict__ boff, int nblk) {
  __shared__ int sdata[256];
  const int t = threadIdx.x;
  sdata[t] = (t < nblk) ? bsum[t] : 0;
  __syncthreads();
  for (int off = 1; off < 256; off <<= 1) {
    int x = 0;
    if (t >= off) x = sdata[t - off];
    __syncthreads();
    if (t >= off) sdata[t] += x;
    __syncthreads();
  }
  boff[t] = (t > 0) ? sdata[t - 1] : 0;
}

// Pass C: add chunk offsets, set rowptr[0]=0
__global__ void scanC_kernel(int* __restrict__ rowptr, const int* __restrict__ boff, int N) {
  int id = blockIdx.x * blockDim.x + threadIdx.x;
  if (id < N) rowptr[1 + id] += boff[id >> 10];
  if (id == 0) rowptr[0] = 0;
}

__global__ void fill_kernel(const int* __restrict__ src, const int* __restrict__ dst,
                            const int* __restrict__ rowptr, int* __restrict__ cursor,
                            int* __restrict__ ssrc, int E) {
  int e = blockIdx.x * blockDim.x + threadIdx.x;
  if (e >= E) return;
  int d = dst[e];
  int pos = rowptr[d] + atomicAdd(&cursor[d], 1);
  ssrc[pos] = src[e];
}

__global__ void dinv_kernel(const int* __restrict__ deg, float* __restrict__ dinv, int N) {
  int i = blockIdx.x * blockDim.x + threadIdx.x;
  if (i < N) dinv[i] = 1.0f / sqrtf((float)deg[i] + 1.0f);
}

// ================= tiled fp32 GEMM: O[N][COLS] = X[N][K] @ W[K][COLS] =================

template <int ROWS, int COLS, int K>
__global__ __launch_bounds__(256) void gemm_kernel(const float* __restrict__ X,
                                                   const float* __restrict__ W,
                                                   float* __restrict__ O, int N) {
  __shared__ float xs[ROWS][K + 4];
  __shared__ float ws[K][COLS];
  const int t = threadIdx.x;
  const int row0 = blockIdx.x * ROWS;

  constexpr int WV = K * COLS / 4;
  for (int i = t; i < WV; i += 256) {
    float4 v = reinterpret_cast<const float4*>(W)[i];
    int base = i * 4;
    int k = base / COLS, c = base % COLS;
    ws[k][c] = v.x; ws[k][c + 1] = v.y; ws[k][c + 2] = v.z; ws[k][c + 3] = v.w;
  }
  constexpr int XV = ROWS * K / 4;
  for (int i = t; i < XV; i += 256) {
    int base = i * 4;
    int r = base / K, k = base % K;
    int row = row0 + r;
    float4 v = make_float4(0.f, 0.f, 0.f, 0.f);
    if (row < N) v = reinterpret_cast<const float4*>(X + (size_t)row * K)[k >> 2];
    *reinterpret_cast<float4*>(&xs[r][k]) = v;
  }
  __syncthreads();

  constexpr int TC = COLS / 4;
  const int tc = t % TC, tr = t / TC;
  const int c0 = tc * 4, r0 = tr * 4;
  float acc[4][4] = {{0.f}};

#pragma unroll 8
  for (int k = 0; k < K; ++k) {
    float a0 = xs[r0 + 0][k];
    float a1 = xs[r0 + 1][k];
    float a2 = xs[r0 + 2][k];
    float a3 = xs[r0 + 3][k];
    float4 b = *reinterpret_cast<const float4*>(&ws[k][c0]);
    acc[0][0] = fmaf(a0, b.x, acc[0][0]); acc[0][1] = fmaf(a0, b.y, acc[0][1]);
    acc[0][2] = fmaf(a0, b.z, acc[0][2]); acc[0][3] = fmaf(a0, b.w, acc[0][3]);
    acc[1][0] = fmaf(a1, b.x, acc[1][0]); acc[1][1] = fmaf(a1, b.y, acc[1][1]);
    acc[1][2] = fmaf(a1, b.z, acc[1][2]); acc[1][3] = fmaf(a1, b.w, acc[1][3]);
    acc[2][0] = fmaf(a2, b.x, acc[2][0]); acc[2][1] = fmaf(a2, b.y, acc[2][1]);
    acc[2][2] = fmaf(a2, b.z, acc[2][2]); acc[2][3] = fmaf(a2, b.w, acc[2][3]);
    acc[3][0] = fmaf(a3, b.x, acc[3][0]); acc[3][1] = fmaf(a3, b.y, acc[3][1]);
    acc[3][2] = fmaf(a3, b.z, acc[3][2]); acc[3][3] = fmaf(a3, b.w, acc[3][3]);
  }

#pragma unroll
  for (int i = 0; i < 4; ++i) {
    int row = row0 + r0 + i;
    if (row < N) {
      float4 o = make_float4(acc[i][0], acc[i][1], acc[i][2], acc[i][3]);
      *reinterpret_cast<float4*>(O + (size_t)row * COLS + c0) = o;
    }
  }
}

// ================= CSR gather aggregation (fused epilogue) =================
// One 64-lane wave per destination node.

// FDIM=64: lane = column. out = relu(sum + h[gid]*di^2 + b)
__global__ __launch_bounds__(256) void gather64_kernel(const int* __restrict__ rowptr,
                                                       const int* __restrict__ ssrc,
                                                       const float* __restrict__ dinv,
                                                       const float* __restrict__ h,
                                                       const float* __restrict__ b,
                                                       float* __restrict__ outb, int N) {
  int gid = (blockIdx.x * 256 + threadIdx.x) >> 6;
  int lane = threadIdx.x & 63;
  if (gid >= N) return;
  int beg = rowptr[gid], end = rowptr[gid + 1];
  float di = dinv[gid];
  float acc = 0.f;
  for (int i = beg; i < end; ++i) {
    int s = ssrc[i];
    float nrm = dinv[s] * di;
    acc = fmaf(h[(size_t)s * 64 + lane], nrm, acc);
  }
  acc = fmaf(h[(size_t)gid * 64 + lane], di * di, acc);
  acc += b[lane];
  outb[(size_t)gid * 64 + lane] = fmaxf(acc, 0.f);
}

// FDIM=32: two edges per iteration (sub = lane>>5 picks edge, col = lane&31)
__global__ __launch_bounds__(256) void gather32_kernel(const int* __restrict__ rowptr,
                                                       const int* __restrict__ ssrc,
                                                       const float* __restrict__ dinv,
                                                       const float* __restrict__ h,
                                                       const float* __restrict__ b,
                                                       float* __restrict__ outb, int N) {
  int gid = (blockIdx.x * 256 + threadIdx.x) >> 6;
  int lane = threadIdx.x & 63;
  int col = lane & 31, sub = lane >> 5;
  if (gid >= N) return;
  int beg = rowptr[gid], end = rowptr[gid + 1];
  float di = dinv[gid];
  float acc = 0.f;
  for (int i = beg + sub; i < end; i += 2) {
    int s = ssrc[i];
    acc = fmaf(h[(size_t)s * 32 + col], dinv[s] * di, acc);
  }
  acc += __shfl_xor(acc, 32, 64);
  if (sub == 0) {
    float v = fmaf(h[(size_t)gid * 32 + col], di * di, acc) + b[col];
    outb[(size_t)gid * 32 + col] = v;
  }
}

// ================= launch =================

extern "C" void kernel_launch(void* const* d_in, const int* in_sizes, int n_in,
                              void* d_out, int out_size, void* d_ws, size_t ws_size,
                              hipStream_t stream) {
  const float* x  = (const float*)d_in[0];
  const int*   ei = (const int*)d_in[1];
  const float* W1 = (const float*)d_in[2];
  const float* b1 = (const float*)d_in[3];
  const float* W2 = (const float*)d_in[4];
  const float* b2 = (const float*)d_in[5];
  float* out = (float*)d_out;

  const int H = in_sizes[3];            // 64
  const int F = in_sizes[2] / H;        // 128
  const int N = in_sizes[0] / F;        // 100000
  const int E = in_sizes[1] / 2;        // 1600000
  const int* src = ei;
  const int* dst = ei + E;

  const int nblk = (N + 1023) / 1024;   // scan chunks (<=256 for N<=262144)

  // workspace layout
  char* w = (char*)d_ws;
  auto alloc = [&](size_t bytes) { char* p = w; w += (bytes + 255) & ~(size_t)255; return p; };
  int*   ideg   = (int*)alloc((size_t)N * 4);
  int*   cursor = (int*)alloc((size_t)N * 4);
  int*   rowptr = (int*)alloc((size_t)(N + 1) * 4);
  int*   bsum   = (int*)alloc(256 * 4);
  int*   boff   = (int*)alloc(256 * 4);
  int*   ssrc   = (int*)alloc((size_t)E * 4);
  float* dinv   = (float*)alloc((size_t)N * 4);
  float* h1     = (float*)alloc((size_t)N * 64 * 4);
  float* buf1   = (float*)alloc((size_t)N * 64 * 4);
  float* h2     = (float*)alloc((size_t)N * 32 * 4);

  hipMemsetAsync(ideg, 0, (size_t)N * 4, stream);
  hipMemsetAsync(cursor, 0, (size_t)N * 4, stream);

  // CSR build
  degi_kernel<<<(E + 255) / 256, 256, 0, stream>>>(dst, ideg, E);
  scanA_kernel<<<nblk, 256, 0, stream>>>(ideg, rowptr + 1, bsum, N);
  scanB_kernel<<<1, 256, 0, stream>>>(bsum, boff, nblk);
  scanC_kernel<<<(N + 255) / 256, 256, 0, stream>>>(rowptr, boff, N);
  dinv_kernel<<<(N + 255) / 256, 256, 0, stream>>>(ideg, dinv, N);
  fill_kernel<<<(E + 255) / 256, 256, 0, stream>>>(src, dst, rowptr, cursor, ssrc, E);

  // layer 1
  gemm_kernel<64, 64, 128><<<(N + 63) / 64, 256, 0, stream>>>(x, W1, h1, N);
  gather64_kernel<<<(N + 3) / 4, 256, 0, stream>>>(rowptr, ssrc, dinv, h1, b1, buf1, N);

  // layer 2
  gemm_kernel<128, 32, 64><<<(N + 127) / 128, 256, 0, stream>>>(buf1, W2, h2, N);
  gather32_kernel<<<(N + 3) / 4, 256, 0, stream>>>(rowptr, ssrc, dinv, h2, b2, out, N);
}

// Round 3
// 342.667 us; speedup vs baseline: 6.1449x; 1.3869x over previous
//
#include <hip/hip_runtime.h>
#include <hip/hip_fp16.h>

// ================= CSR build =================

__global__ void degi_kernel(const int* __restrict__ dst, int* __restrict__ deg, int E) {
  int e = blockIdx.x * blockDim.x + threadIdx.x;
  if (e < E) atomicAdd(&deg[dst[e]], 1);
}

// Pass A: per-1024-chunk inclusive scan -> rowptr[1+i]; chunk sums -> bsum
__global__ __launch_bounds__(256) void scanA_kernel(const int* __restrict__ deg,
                                                    int* __restrict__ incl1,  // rowptr+1
                                                    int* __restrict__ bsum, int N) {
  __shared__ int sdata[256];
  const int t = threadIdx.x;
  const int base = blockIdx.x * 1024 + t * 4;
  int v[4];
  int s = 0;
#pragma unroll
  for (int j = 0; j < 4; ++j) {
    v[j] = (base + j < N) ? deg[base + j] : 0;
    s += v[j];
  }
  sdata[t] = s;
  __syncthreads();
  for (int off = 1; off < 256; off <<= 1) {
    int x = 0;
    if (t >= off) x = sdata[t - off];
    __syncthreads();
    if (t >= off) sdata[t] += x;
    __syncthreads();
  }
  int run = (t > 0) ? sdata[t - 1] : 0;
#pragma unroll
  for (int j = 0; j < 4; ++j) {
    run += v[j];
    if (base + j < N) incl1[base + j] = run;
  }
  if (t == 255) bsum[blockIdx.x] = sdata[255];
}

// Pass B: single block, exclusive scan of up to 256 chunk sums -> boff
__global__ __launch_bounds__(256) void scanB_kernel(const int* __restrict__ bsum,
                                                    int* __restrict__ boff, int nblk) {
  __shared__ int sdata[256];
  const int t = threadIdx.x;
  sdata[t] = (t < nblk) ? bsum[t] : 0;
  __syncthreads();
  for (int off = 1; off < 256; off <<= 1) {
    int x = 0;
    if (t >= off) x = sdata[t - off];
    __syncthreads();
    if (t >= off) sdata[t] += x;
    __syncthreads();
  }
  boff[t] = (t > 0) ? sdata[t - 1] : 0;
}

// Pass C: add chunk offsets, set rowptr[0]=0
__global__ void scanC_kernel(int* __restrict__ rowptr, const int* __restrict__ boff, int N) {
  int id = blockIdx.x * blockDim.x + threadIdx.x;
  if (id < N) rowptr[1 + id] += boff[id >> 10];
  if (id == 0) rowptr[0] = 0;
}

__global__ void dinv_kernel(const int* __restrict__ deg, float* __restrict__ dinv, int N) {
  int i = blockIdx.x * blockDim.x + threadIdx.x;
  if (i < N) dinv[i] = 1.0f / sqrtf((float)deg[i] + 1.0f);
}

// fill: cursor pre-initialized to rowptr (d2d copy). ep[pos] = {src, bits(norm)}
__global__ void fill_kernel(const int* __restrict__ src, const int* __restrict__ dst,
                            int* __restrict__ cursor, const float* __restrict__ dinv,
                            int2* __restrict__ ep, int E) {
  int e = blockIdx.x * blockDim.x + threadIdx.x;
  if (e >= E) return;
  int d = dst[e];
  int s = src[e];
  int pos = atomicAdd(&cursor[d], 1);
  float w = dinv[s] * dinv[d];
  ep[pos] = make_int2(s, __float_as_int(w));
}

// ================= tiled fp32 GEMM: O[N][COLS] = X[N][K] @ W[K][COLS] =================
// 256 threads, 4x4 micro-tile, optional fp16 output.

template <int ROWS, int COLS, int K, bool HALF_OUT>
__global__ __launch_bounds__(256) void gemm_kernel(const float* __restrict__ X,
                                                   const float* __restrict__ W,
                                                   void* __restrict__ O, int N) {
  __shared__ float xs[ROWS][K + 4];
  __shared__ float ws[K][COLS];
  const int t = threadIdx.x;
  const int row0 = blockIdx.x * ROWS;

  constexpr int WV = K * COLS / 4;
  for (int i = t; i < WV; i += 256) {
    float4 v = reinterpret_cast<const float4*>(W)[i];
    int base = i * 4;
    int k = base / COLS, c = base % COLS;
    ws[k][c] = v.x; ws[k][c + 1] = v.y; ws[k][c + 2] = v.z; ws[k][c + 3] = v.w;
  }
  constexpr int XV = ROWS * K / 4;
  for (int i = t; i < XV; i += 256) {
    int base = i * 4;
    int r = base / K, k = base % K;
    int row = row0 + r;
    float4 v = make_float4(0.f, 0.f, 0.f, 0.f);
    if (row < N) v = reinterpret_cast<const float4*>(X + (size_t)row * K)[k >> 2];
    *reinterpret_cast<float4*>(&xs[r][k]) = v;
  }
  __syncthreads();

  constexpr int TC = COLS / 4;
  const int tc = t % TC, tr = t / TC;
  const int c0 = tc * 4, r0 = tr * 4;
  float acc[4][4] = {{0.f}};

#pragma unroll 8
  for (int k = 0; k < K; ++k) {
    float a0 = xs[r0 + 0][k];
    float a1 = xs[r0 + 1][k];
    float a2 = xs[r0 + 2][k];
    float a3 = xs[r0 + 3][k];
    float4 b = *reinterpret_cast<const float4*>(&ws[k][c0]);
    acc[0][0] = fmaf(a0, b.x, acc[0][0]); acc[0][1] = fmaf(a0, b.y, acc[0][1]);
    acc[0][2] = fmaf(a0, b.z, acc[0][2]); acc[0][3] = fmaf(a0, b.w, acc[0][3]);
    acc[1][0] = fmaf(a1, b.x, acc[1][0]); acc[1][1] = fmaf(a1, b.y, acc[1][1]);
    acc[1][2] = fmaf(a1, b.z, acc[1][2]); acc[1][3] = fmaf(a1, b.w, acc[1][3]);
    acc[2][0] = fmaf(a2, b.x, acc[2][0]); acc[2][1] = fmaf(a2, b.y, acc[2][1]);
    acc[2][2] = fmaf(a2, b.z, acc[2][2]); acc[2][3] = fmaf(a2, b.w, acc[2][3]);
    acc[3][0] = fmaf(a3, b.x, acc[3][0]); acc[3][1] = fmaf(a3, b.y, acc[3][1]);
    acc[3][2] = fmaf(a3, b.z, acc[3][2]); acc[3][3] = fmaf(a3, b.w, acc[3][3]);
  }

#pragma unroll
  for (int i = 0; i < 4; ++i) {
    int row = row0 + r0 + i;
    if (row < N) {
      if constexpr (HALF_OUT) {
        __half2 p01 = __floats2half2_rn(acc[i][0], acc[i][1]);
        __half2 p23 = __floats2half2_rn(acc[i][2], acc[i][3]);
        union { __half2 h2[2]; uint2 u; } cvt;
        cvt.h2[0] = p01; cvt.h2[1] = p23;
        *reinterpret_cast<uint2*>((__half*)O + (size_t)row * COLS + c0) = cvt.u;
      } else {
        float4 o = make_float4(acc[i][0], acc[i][1], acc[i][2], acc[i][3]);
        *reinterpret_cast<float4*>((float*)O + (size_t)row * COLS + c0) = o;
      }
    }
  }
}

// ================= CSR gather aggregation (fused epilogue) =================
// One 64-lane wave per destination node; 4x unroll for MLP.

// FDIM=64: lane = column. out = relu(sum + h[gid]*di^2 + b)
__global__ __launch_bounds__(256) void gather64_kernel(const int* __restrict__ rowptr,
                                                       const int2* __restrict__ ep,
                                                       const float* __restrict__ dinv,
                                                       const __half* __restrict__ h,
                                                       const float* __restrict__ b,
                                                       float* __restrict__ outb, int N) {
  int gid = (blockIdx.x * 256 + threadIdx.x) >> 6;
  int lane = threadIdx.x & 63;
  if (gid >= N) return;
  int beg = rowptr[gid], end = rowptr[gid + 1];
  float di = dinv[gid];
  float acc0 = 0.f, acc1 = 0.f, acc2 = 0.f, acc3 = 0.f;
  int i = beg;
  for (; i + 4 <= end; i += 4) {
    int2 p0 = ep[i + 0];
    int2 p1 = ep[i + 1];
    int2 p2 = ep[i + 2];
    int2 p3 = ep[i + 3];
    float v0 = __half2float(h[(size_t)p0.x * 64 + lane]);
    float v1 = __half2float(h[(size_t)p1.x * 64 + lane]);
    float v2 = __half2float(h[(size_t)p2.x * 64 + lane]);
    float v3 = __half2float(h[(size_t)p3.x * 64 + lane]);
    acc0 = fmaf(v0, __int_as_float(p0.y), acc0);
    acc1 = fmaf(v1, __int_as_float(p1.y), acc1);
    acc2 = fmaf(v2, __int_as_float(p2.y), acc2);
    acc3 = fmaf(v3, __int_as_float(p3.y), acc3);
  }
  for (; i < end; ++i) {
    int2 p = ep[i];
    acc0 = fmaf(__half2float(h[(size_t)p.x * 64 + lane]), __int_as_float(p.y), acc0);
  }
  float acc = (acc0 + acc1) + (acc2 + acc3);
  acc = fmaf(__half2float(h[(size_t)gid * 64 + lane]), di * di, acc);
  acc += b[lane];
  outb[(size_t)gid * 64 + lane] = fmaxf(acc, 0.f);
}

// FDIM=32: half-waves take alternate edges; 4x unroll each.
__global__ __launch_bounds__(256) void gather32_kernel(const int* __restrict__ rowptr,
                                                       const int2* __restrict__ ep,
                                                       const float* __restrict__ dinv,
                                                       const __half* __restrict__ h,
                                                       const float* __restrict__ b,
                                                       float* __restrict__ outb, int N) {
  int gid = (blockIdx.x * 256 + threadIdx.x) >> 6;
  int lane = threadIdx.x & 63;
  int col = lane & 31, sub = lane >> 5;
  if (gid >= N) return;
  int beg = rowptr[gid], end = rowptr[gid + 1];
  float di = dinv[gid];
  float acc0 = 0.f, acc1 = 0.f, acc2 = 0.f, acc3 = 0.f;
  int i = beg + sub;
  for (; i + 7 <= end; i += 8) {
    int2 p0 = ep[i + 0];
    int2 p1 = ep[i + 2];
    int2 p2 = ep[i + 4];
    int2 p3 = ep[i + 6];
    float v0 = __half2float(h[(size_t)p0.x * 32 + col]);
    float v1 = __half2float(h[(size_t)p1.x * 32 + col]);
    float v2 = __half2float(h[(size_t)p2.x * 32 + col]);
    float v3 = __half2float(h[(size_t)p3.x * 32 + col]);
    acc0 = fmaf(v0, __int_as_float(p0.y), acc0);
    acc1 = fmaf(v1, __int_as_float(p1.y), acc1);
    acc2 = fmaf(v2, __int_as_float(p2.y), acc2);
    acc3 = fmaf(v3, __int_as_float(p3.y), acc3);
  }
  for (; i < end; i += 2) {
    int2 p = ep[i];
    acc0 = fmaf(__half2float(h[(size_t)p.x * 32 + col]), __int_as_float(p.y), acc0);
  }
  float acc = (acc0 + acc1) + (acc2 + acc3);
  acc += __shfl_xor(acc, 32, 64);
  if (sub == 0) {
    float v = fmaf(__half2float(h[(size_t)gid * 32 + col]), di * di, acc) + b[col];
    outb[(size_t)gid * 32 + col] = v;
  }
}

// ================= launch =================

extern "C" void kernel_launch(void* const* d_in, const int* in_sizes, int n_in,
                              void* d_out, int out_size, void* d_ws, size_t ws_size,
                              hipStream_t stream) {
  const float* x  = (const float*)d_in[0];
  const int*   ei = (const int*)d_in[1];
  const float* W1 = (const float*)d_in[2];
  const float* b1 = (const float*)d_in[3];
  const float* W2 = (const float*)d_in[4];
  const float* b2 = (const float*)d_in[5];
  float* out = (float*)d_out;

  const int H = in_sizes[3];            // 64
  const int F = in_sizes[2] / H;        // 128
  const int N = in_sizes[0] / F;        // 100000
  const int E = in_sizes[1] / 2;        // 1600000
  const int* src = ei;
  const int* dst = ei + E;

  const int nblk = (N + 1023) / 1024;   // scan chunks (<=256 for N<=262144)

  // workspace layout
  char* w = (char*)d_ws;
  auto alloc = [&](size_t bytes) { char* p = w; w += (bytes + 255) & ~(size_t)255; return p; };
  int*    ideg   = (int*)alloc((size_t)N * 4);
  int*    cursor = (int*)alloc((size_t)N * 4);
  int*    rowptr = (int*)alloc((size_t)(N + 1) * 4);
  int*    bsum   = (int*)alloc(256 * 4);
  int*    boff   = (int*)alloc(256 * 4);
  int2*   ep     = (int2*)alloc((size_t)E * 8);
  float*  dinv   = (float*)alloc((size_t)N * 4);
  __half* h1     = (__half*)alloc((size_t)N * 64 * 2);
  float*  buf1   = (float*)alloc((size_t)N * 64 * 4);
  __half* h2     = (__half*)alloc((size_t)N * 32 * 2);

  hipMemsetAsync(ideg, 0, (size_t)N * 4, stream);

  // CSR build
  degi_kernel<<<(E + 255) / 256, 256, 0, stream>>>(dst, ideg, E);
  scanA_kernel<<<nblk, 256, 0, stream>>>(ideg, rowptr + 1, bsum, N);
  scanB_kernel<<<1, 256, 0, stream>>>(bsum, boff, nblk);
  scanC_kernel<<<(N + 255) / 256, 256, 0, stream>>>(rowptr, boff, N);
  dinv_kernel<<<(N + 255) / 256, 256, 0, stream>>>(ideg, dinv, N);
  hipMemcpyAsync(cursor, rowptr, (size_t)N * 4, hipMemcpyDeviceToDevice, stream);
  fill_kernel<<<(E + 255) / 256, 256, 0, stream>>>(src, dst, cursor, dinv, ep, E);

  // layer 1
  gemm_kernel<64, 64, 128, true><<<(N + 63) / 64, 256, 0, stream>>>(x, W1, h1, N);
  gather64_kernel<<<(N + 3) / 4, 256, 0, stream>>>(rowptr, ep, dinv, h1, b1, buf1, N);

  // layer 2
  gemm_kernel<128, 32, 64, true><<<(N + 127) / 128, 256, 0, stream>>>(buf1, W2, h2, N);
  gather32_kernel<<<(N + 3) / 4, 256, 0, stream>>>(rowptr, ep, dinv, h2, b2, out, N);
}

// Round 4
// 257.809 us; speedup vs baseline: 8.1676x; 1.3292x over previous
//
#include <hip/hip_runtime.h>
#include <hip/hip_fp16.h>

// ================= CSR build =================

// degree + within-bucket position in one pass (atomic return feeds coalesced store)
__global__ void degpos_kernel(const int* __restrict__ dst, int* __restrict__ deg,
                              int* __restrict__ posbuf, int E) {
  int t = blockIdx.x * blockDim.x + threadIdx.x;
  int e0 = t * 4;
  if (e0 + 4 <= E) {
    int4 d4 = *reinterpret_cast<const int4*>(dst + e0);
    int p0 = atomicAdd(&deg[d4.x], 1);
    int p1 = atomicAdd(&deg[d4.y], 1);
    int p2 = atomicAdd(&deg[d4.z], 1);
    int p3 = atomicAdd(&deg[d4.w], 1);
    *reinterpret_cast<int4*>(posbuf + e0) = make_int4(p0, p1, p2, p3);
  } else {
    for (int e = e0; e < E; ++e) posbuf[e] = atomicAdd(&deg[dst[e]], 1);
  }
}

// Pass A: per-1024-chunk inclusive scan -> rowptr[1+i]; chunk sums -> bsum
__global__ __launch_bounds__(256) void scanA_kernel(const int* __restrict__ deg,
                                                    int* __restrict__ incl1,
                                                    int* __restrict__ bsum, int N) {
  __shared__ int sdata[256];
  const int t = threadIdx.x;
  const int base = blockIdx.x * 1024 + t * 4;
  int v[4];
  int s = 0;
#pragma unroll
  for (int j = 0; j < 4; ++j) {
    v[j] = (base + j < N) ? deg[base + j] : 0;
    s += v[j];
  }
  sdata[t] = s;
  __syncthreads();
  for (int off = 1; off < 256; off <<= 1) {
    int x = 0;
    if (t >= off) x = sdata[t - off];
    __syncthreads();
    if (t >= off) sdata[t] += x;
    __syncthreads();
  }
  int run = (t > 0) ? sdata[t - 1] : 0;
#pragma unroll
  for (int j = 0; j < 4; ++j) {
    run += v[j];
    if (base + j < N) incl1[base + j] = run;
  }
  if (t == 255) bsum[blockIdx.x] = sdata[255];
}

__global__ __launch_bounds__(256) void scanB_kernel(const int* __restrict__ bsum,
                                                    int* __restrict__ boff, int nblk) {
  __shared__ int sdata[256];
  const int t = threadIdx.x;
  sdata[t] = (t < nblk) ? bsum[t] : 0;
  __syncthreads();
  for (int off = 1; off < 256; off <<= 1) {
    int x = 0;
    if (t >= off) x = sdata[t - off];
    __syncthreads();
    if (t >= off) sdata[t] += x;
    __syncthreads();
  }
  boff[t] = (t > 0) ? sdata[t - 1] : 0;
}

__global__ void scanC_kernel(int* __restrict__ rowptr, const int* __restrict__ boff, int N) {
  int id = blockIdx.x * blockDim.x + threadIdx.x;
  if (id < N) rowptr[1 + id] += boff[id >> 10];
  if (id == 0) rowptr[0] = 0;
}

__global__ void dinv_kernel(const int* __restrict__ deg, float* __restrict__ dinv, int N) {
  int i = blockIdx.x * blockDim.x + threadIdx.x;
  if (i < N) dinv[i] = 1.0f / sqrtf((float)deg[i] + 1.0f);
}

// atomic-free scatter: ssrc[rowptr[d] + posbuf[e]] = src[e]
__global__ void fillpos_kernel(const int* __restrict__ src, const int* __restrict__ dst,
                               const int* __restrict__ posbuf, const int* __restrict__ rowptr,
                               int* __restrict__ ssrc, int E) {
  int t = blockIdx.x * blockDim.x + threadIdx.x;
  int e0 = t * 4;
  if (e0 + 4 <= E) {
    int4 s4 = *reinterpret_cast<const int4*>(src + e0);
    int4 d4 = *reinterpret_cast<const int4*>(dst + e0);
    int4 p4 = *reinterpret_cast<const int4*>(posbuf + e0);
    ssrc[rowptr[d4.x] + p4.x] = s4.x;
    ssrc[rowptr[d4.y] + p4.y] = s4.y;
    ssrc[rowptr[d4.z] + p4.z] = s4.z;
    ssrc[rowptr[d4.w] + p4.w] = s4.w;
  } else {
    for (int e = e0; e < E; ++e) ssrc[rowptr[dst[e]] + posbuf[e]] = src[e];
  }
}

// ================= tiled fp32 GEMM: G[N][COLS] = dinv .* (X[N][K] @ W[K][COLS]), fp16 out ====

template <int ROWS, int COLS, int K>
__global__ __launch_bounds__(256) void gemm_kernel(const float* __restrict__ X,
                                                   const float* __restrict__ W,
                                                   const float* __restrict__ dinv,
                                                   __half* __restrict__ O, int N) {
  __shared__ float xs[ROWS][K + 4];
  __shared__ float ws[K][COLS];
  const int t = threadIdx.x;
  const int row0 = blockIdx.x * ROWS;

  constexpr int WV = K * COLS / 4;
  for (int i = t; i < WV; i += 256) {
    float4 v = reinterpret_cast<const float4*>(W)[i];
    int base = i * 4;
    int k = base / COLS, c = base % COLS;
    ws[k][c] = v.x; ws[k][c + 1] = v.y; ws[k][c + 2] = v.z; ws[k][c + 3] = v.w;
  }
  constexpr int XV = ROWS * K / 4;
  for (int i = t; i < XV; i += 256) {
    int base = i * 4;
    int r = base / K, k = base % K;
    int row = row0 + r;
    float4 v = make_float4(0.f, 0.f, 0.f, 0.f);
    if (row < N) v = reinterpret_cast<const float4*>(X + (size_t)row * K)[k >> 2];
    *reinterpret_cast<float4*>(&xs[r][k]) = v;
  }
  __syncthreads();

  constexpr int TC = COLS / 4;
  const int tc = t % TC, tr = t / TC;
  const int c0 = tc * 4, r0 = tr * 4;
  float acc[4][4] = {{0.f}};

#pragma unroll 8
  for (int k = 0; k < K; ++k) {
    float a0 = xs[r0 + 0][k];
    float a1 = xs[r0 + 1][k];
    float a2 = xs[r0 + 2][k];
    float a3 = xs[r0 + 3][k];
    float4 b = *reinterpret_cast<const float4*>(&ws[k][c0]);
    acc[0][0] = fmaf(a0, b.x, acc[0][0]); acc[0][1] = fmaf(a0, b.y, acc[0][1]);
    acc[0][2] = fmaf(a0, b.z, acc[0][2]); acc[0][3] = fmaf(a0, b.w, acc[0][3]);
    acc[1][0] = fmaf(a1, b.x, acc[1][0]); acc[1][1] = fmaf(a1, b.y, acc[1][1]);
    acc[1][2] = fmaf(a1, b.z, acc[1][2]); acc[1][3] = fmaf(a1, b.w, acc[1][3]);
    acc[2][0] = fmaf(a2, b.x, acc[2][0]); acc[2][1] = fmaf(a2, b.y, acc[2][1]);
    acc[2][2] = fmaf(a2, b.z, acc[2][2]); acc[2][3] = fmaf(a2, b.w, acc[2][3]);
    acc[3][0] = fmaf(a3, b.x, acc[3][0]); acc[3][1] = fmaf(a3, b.y, acc[3][1]);
    acc[3][2] = fmaf(a3, b.z, acc[3][2]); acc[3][3] = fmaf(a3, b.w, acc[3][3]);
  }

#pragma unroll
  for (int i = 0; i < 4; ++i) {
    int row = row0 + r0 + i;
    if (row < N) {
      float di = dinv[row];
      __half2 p01 = __floats2half2_rn(acc[i][0] * di, acc[i][1] * di);
      __half2 p23 = __floats2half2_rn(acc[i][2] * di, acc[i][3] * di);
      union { __half2 h2[2]; uint2 u; } cvt;
      cvt.h2[0] = p01; cvt.h2[1] = p23;
      *reinterpret_cast<uint2*>(O + (size_t)row * COLS + c0) = cvt.u;
    }
  }
}

// ================= CSR gather aggregation (fused epilogue) =================
// g rows are fp16, pre-scaled by dinv[src]. Pure adds per edge.

// FDIM=64: 2 edges per wave-iteration (sub=lane>>5), half2 per lane, 4x unroll.
// out = relu(dinv[gid]*(sum + g[gid]) + b)
__global__ __launch_bounds__(256) void gather64_kernel(const int* __restrict__ rowptr,
                                                       const int* __restrict__ ssrc,
                                                       const float* __restrict__ dinv,
                                                       const __half2* __restrict__ g,
                                                       const float2* __restrict__ bias,
                                                       float2* __restrict__ outb, int N) {
  int gid = (blockIdx.x * 256 + threadIdx.x) >> 6;
  int lane = threadIdx.x & 63;
  int col = lane & 31, sub = lane >> 5;
  if (gid >= N) return;
  int beg = rowptr[gid], end = rowptr[gid + 1];
  float2 a0 = {0.f, 0.f}, a1 = {0.f, 0.f}, a2 = {0.f, 0.f}, a3 = {0.f, 0.f};
  int i = beg + sub;
  for (; i + 7 <= end; i += 8) {
    int s0 = ssrc[i + 0];
    int s1 = ssrc[i + 2];
    int s2 = ssrc[i + 4];
    int s3 = ssrc[i + 6];
    float2 v0 = __half22float2(g[(size_t)s0 * 32 + col]);
    float2 v1 = __half22float2(g[(size_t)s1 * 32 + col]);
    float2 v2 = __half22float2(g[(size_t)s2 * 32 + col]);
    float2 v3 = __half22float2(g[(size_t)s3 * 32 + col]);
    a0.x += v0.x; a0.y += v0.y;
    a1.x += v1.x; a1.y += v1.y;
    a2.x += v2.x; a2.y += v2.y;
    a3.x += v3.x; a3.y += v3.y;
  }
  for (; i < end; i += 2) {
    float2 v = __half22float2(g[(size_t)ssrc[i] * 32 + col]);
    a0.x += v.x; a0.y += v.y;
  }
  float2 acc = make_float2((a0.x + a1.x) + (a2.x + a3.x), (a0.y + a1.y) + (a2.y + a3.y));
  acc.x += __shfl_xor(acc.x, 32, 64);
  acc.y += __shfl_xor(acc.y, 32, 64);
  if (sub == 0) {
    float2 gs = __half22float2(g[(size_t)gid * 32 + col]);
    float di = dinv[gid];
    float2 bb = bias[col];
    float ox = fmaxf(fmaf(di, acc.x + gs.x, bb.x), 0.f);
    float oy = fmaxf(fmaf(di, acc.y + gs.y, bb.y), 0.f);
    outb[(size_t)gid * 32 + col] = make_float2(ox, oy);
  }
}

// FDIM=32: 4 edges per wave-iteration (sub=lane>>4), half2 per lane, 4x unroll.
__global__ __launch_bounds__(256) void gather32_kernel(const int* __restrict__ rowptr,
                                                       const int* __restrict__ ssrc,
                                                       const float* __restrict__ dinv,
                                                       const __half2* __restrict__ g,
                                                       const float2* __restrict__ bias,
                                                       float2* __restrict__ outb, int N) {
  int gid = (blockIdx.x * 256 + threadIdx.x) >> 6;
  int lane = threadIdx.x & 63;
  int col = lane & 15, sub = lane >> 4;
  if (gid >= N) return;
  int beg = rowptr[gid], end = rowptr[gid + 1];
  float2 a0 = {0.f, 0.f}, a1 = {0.f, 0.f}, a2 = {0.f, 0.f}, a3 = {0.f, 0.f};
  int i = beg + sub;
  for (; i + 13 <= end; i += 16) {
    int s0 = ssrc[i + 0];
    int s1 = ssrc[i + 4];
    int s2 = ssrc[i + 8];
    int s3 = ssrc[i + 12];
    float2 v0 = __half22float2(g[(size_t)s0 * 16 + col]);
    float2 v1 = __half22float2(g[(size_t)s1 * 16 + col]);
    float2 v2 = __half22float2(g[(size_t)s2 * 16 + col]);
    float2 v3 = __half22float2(g[(size_t)s3 * 16 + col]);
    a0.x += v0.x; a0.y += v0.y;
    a1.x += v1.x; a1.y += v1.y;
    a2.x += v2.x; a2.y += v2.y;
    a3.x += v3.x; a3.y += v3.y;
  }
  for (; i < end; i += 4) {
    float2 v = __half22float2(g[(size_t)ssrc[i] * 16 + col]);
    a0.x += v.x; a0.y += v.y;
  }
  float2 acc = make_float2((a0.x + a1.x) + (a2.x + a3.x), (a0.y + a1.y) + (a2.y + a3.y));
  acc.x += __shfl_xor(acc.x, 16, 64);
  acc.y += __shfl_xor(acc.y, 16, 64);
  acc.x += __shfl_xor(acc.x, 32, 64);
  acc.y += __shfl_xor(acc.y, 32, 64);
  if (sub == 0) {
    float2 gs = __half22float2(g[(size_t)gid * 16 + col]);
    float di = dinv[gid];
    float2 bb = bias[col];
    float ox = fmaf(di, acc.x + gs.x, bb.x);
    float oy = fmaf(di, acc.y + gs.y, bb.y);
    outb[(size_t)gid * 16 + col] = make_float2(ox, oy);
  }
}

// ================= launch =================

extern "C" void kernel_launch(void* const* d_in, const int* in_sizes, int n_in,
                              void* d_out, int out_size, void* d_ws, size_t ws_size,
                              hipStream_t stream) {
  const float* x  = (const float*)d_in[0];
  const int*   ei = (const int*)d_in[1];
  const float* W1 = (const float*)d_in[2];
  const float* b1 = (const float*)d_in[3];
  const float* W2 = (const float*)d_in[4];
  const float* b2 = (const float*)d_in[5];
  float* out = (float*)d_out;

  const int H = in_sizes[3];            // 64
  const int F = in_sizes[2] / H;        // 128
  const int N = in_sizes[0] / F;        // 100000
  const int E = in_sizes[1] / 2;        // 1600000
  const int* src = ei;
  const int* dst = ei + E;

  const int nblk = (N + 1023) / 1024;

  char* w = (char*)d_ws;
  auto alloc = [&](size_t bytes) { char* p = w; w += (bytes + 255) & ~(size_t)255; return p; };
  int*    ideg   = (int*)alloc((size_t)N * 4);
  int*    rowptr = (int*)alloc((size_t)(N + 1) * 4);
  int*    bsum   = (int*)alloc(256 * 4);
  int*    boff   = (int*)alloc(256 * 4);
  int*    posbuf = (int*)alloc((size_t)E * 4);
  int*    ssrc   = (int*)alloc((size_t)E * 4);
  float*  dinv   = (float*)alloc((size_t)N * 4);
  __half* g1     = (__half*)alloc((size_t)N * 64 * 2);
  float*  buf1   = (float*)alloc((size_t)N * 64 * 4);
  __half* g2     = (__half*)alloc((size_t)N * 32 * 2);

  hipMemsetAsync(ideg, 0, (size_t)N * 4, stream);

  // CSR build
  degpos_kernel<<<((E + 3) / 4 + 255) / 256, 256, 0, stream>>>(dst, ideg, posbuf, E);
  scanA_kernel<<<nblk, 256, 0, stream>>>(ideg, rowptr + 1, bsum, N);
  scanB_kernel<<<1, 256, 0, stream>>>(bsum, boff, nblk);
  scanC_kernel<<<(N + 255) / 256, 256, 0, stream>>>(rowptr, boff, N);
  dinv_kernel<<<(N + 255) / 256, 256, 0, stream>>>(ideg, dinv, N);
  fillpos_kernel<<<((E + 3) / 4 + 255) / 256, 256, 0, stream>>>(src, dst, posbuf, rowptr, ssrc, E);

  // layer 1: g1 = dinv .* (x @ W1)   (fp16)
  gemm_kernel<64, 64, 128><<<(N + 63) / 64, 256, 0, stream>>>(x, W1, dinv, g1, N);
  gather64_kernel<<<(N + 3) / 4, 256, 0, stream>>>(rowptr, ssrc, dinv,
      (const __half2*)g1, (const float2*)b1, (float2*)buf1, N);

  // layer 2: g2 = dinv .* (r1 @ W2)  (fp16)
  gemm_kernel<128, 32, 64><<<(N + 127) / 128, 256, 0, stream>>>(buf1, W2, dinv, g2, N);
  gather32_kernel<<<(N + 3) / 4, 256, 0, stream>>>(rowptr, ssrc, dinv,
      (const __half2*)g2, (const float2*)b2, (float2*)out, N);
}

// Round 5
// 248.545 us; speedup vs baseline: 8.4720x; 1.0373x over previous
//
#include <hip/hip_runtime.h>
#include <hip/hip_fp16.h>

// ================= CSR build =================

// degree + within-bucket position in one pass; 2 edges/thread for full occupancy
__global__ void degpos_kernel(const int* __restrict__ dst, int* __restrict__ deg,
                              int* __restrict__ posbuf, int E) {
  int t = blockIdx.x * blockDim.x + threadIdx.x;
  int e0 = t * 2;
  if (e0 + 2 <= E) {
    int2 d2 = *reinterpret_cast<const int2*>(dst + e0);
    int p0 = atomicAdd(&deg[d2.x], 1);
    int p1 = atomicAdd(&deg[d2.y], 1);
    *reinterpret_cast<int2*>(posbuf + e0) = make_int2(p0, p1);
  } else if (e0 < E) {
    posbuf[e0] = atomicAdd(&deg[dst[e0]], 1);
  }
}

// Pass A: per-1024-chunk inclusive scan -> rowptr[1+i]; chunk sums -> bsum
__global__ __launch_bounds__(256) void scanA_kernel(const int* __restrict__ deg,
                                                    int* __restrict__ incl1,
                                                    int* __restrict__ bsum, int N) {
  __shared__ int sdata[256];
  const int t = threadIdx.x;
  const int base = blockIdx.x * 1024 + t * 4;
  int v[4];
  int s = 0;
#pragma unroll
  for (int j = 0; j < 4; ++j) {
    v[j] = (base + j < N) ? deg[base + j] : 0;
    s += v[j];
  }
  sdata[t] = s;
  __syncthreads();
  for (int off = 1; off < 256; off <<= 1) {
    int x = 0;
    if (t >= off) x = sdata[t - off];
    __syncthreads();
    if (t >= off) sdata[t] += x;
    __syncthreads();
  }
  int run = (t > 0) ? sdata[t - 1] : 0;
#pragma unroll
  for (int j = 0; j < 4; ++j) {
    run += v[j];
    if (base + j < N) incl1[base + j] = run;
  }
  if (t == 255) bsum[blockIdx.x] = sdata[255];
}

__global__ __launch_bounds__(256) void scanB_kernel(const int* __restrict__ bsum,
                                                    int* __restrict__ boff, int nblk) {
  __shared__ int sdata[256];
  const int t = threadIdx.x;
  sdata[t] = (t < nblk) ? bsum[t] : 0;
  __syncthreads();
  for (int off = 1; off < 256; off <<= 1) {
    int x = 0;
    if (t >= off) x = sdata[t - off];
    __syncthreads();
    if (t >= off) sdata[t] += x;
    __syncthreads();
  }
  boff[t] = (t > 0) ? sdata[t - 1] : 0;
}

__global__ void scanC_kernel(int* __restrict__ rowptr, const int* __restrict__ boff, int N) {
  int id = blockIdx.x * blockDim.x + threadIdx.x;
  if (id < N) rowptr[1 + id] += boff[id >> 10];
  if (id == 0) rowptr[0] = 0;
}

__global__ void dinv_kernel(const int* __restrict__ deg, float* __restrict__ dinv, int N) {
  int i = blockIdx.x * blockDim.x + threadIdx.x;
  if (i < N) dinv[i] = 1.0f / sqrtf((float)deg[i] + 1.0f);
}

// atomic-free scatter: ssrc[rowptr[d] + posbuf[e]] = src[e]; 2 edges/thread
__global__ void fillpos_kernel(const int* __restrict__ src, const int* __restrict__ dst,
                               const int* __restrict__ posbuf, const int* __restrict__ rowptr,
                               int* __restrict__ ssrc, int E) {
  int t = blockIdx.x * blockDim.x + threadIdx.x;
  int e0 = t * 2;
  if (e0 + 2 <= E) {
    int2 s2 = *reinterpret_cast<const int2*>(src + e0);
    int2 d2 = *reinterpret_cast<const int2*>(dst + e0);
    int2 p2 = *reinterpret_cast<const int2*>(posbuf + e0);
    ssrc[rowptr[d2.x] + p2.x] = s2.x;
    ssrc[rowptr[d2.y] + p2.y] = s2.y;
  } else if (e0 < E) {
    ssrc[rowptr[dst[e0]] + posbuf[e0]] = src[e0];
  }
}

// ========== layer-1 GEMM (K4 form, FMA-bound): G = dinv .* (X @ W), fp16 out ==========
// ROWS=64, COLS=64, K=128. Per 4k: 8 ds_read_b128 + 64 FMA per thread.

template <int ROWS, int COLS, int K>
__global__ __launch_bounds__(256) void gemmk4_kernel(const float* __restrict__ X,
                                                     const float* __restrict__ W,
                                                     const float* __restrict__ dinv,
                                                     __half* __restrict__ O, int N) {
  __shared__ float xs[ROWS][K + 4];
  __shared__ float ws[K][COLS];
  const int t = threadIdx.x;
  const int row0 = blockIdx.x * ROWS;

  constexpr int WV = K * COLS / 4;
  for (int i = t; i < WV; i += 256) {
    float4 v = reinterpret_cast<const float4*>(W)[i];
    int base = i * 4;
    int k = base / COLS, c = base % COLS;
    ws[k][c] = v.x; ws[k][c + 1] = v.y; ws[k][c + 2] = v.z; ws[k][c + 3] = v.w;
  }
  constexpr int XV = ROWS * K / 4;
  for (int i = t; i < XV; i += 256) {
    int base = i * 4;
    int r = base / K, k = base % K;
    int row = row0 + r;
    float4 v = make_float4(0.f, 0.f, 0.f, 0.f);
    if (row < N) v = reinterpret_cast<const float4*>(X + (size_t)row * K)[k >> 2];
    *reinterpret_cast<float4*>(&xs[r][k]) = v;
  }
  __syncthreads();

  constexpr int TC = COLS / 4;
  const int tc = t % TC, tr = t / TC;
  const int c0 = tc * 4, r0 = tr * 4;
  float acc[4][4] = {{0.f}};

  for (int k = 0; k < K; k += 4) {
    float4 a[4], b[4];
#pragma unroll
    for (int i = 0; i < 4; ++i)
      a[i] = *reinterpret_cast<const float4*>(&xs[r0 + i][k]);
#pragma unroll
    for (int j = 0; j < 4; ++j)
      b[j] = *reinterpret_cast<const float4*>(&ws[k + j][c0]);
#pragma unroll
    for (int i = 0; i < 4; ++i) {
      acc[i][0] = fmaf(a[i].x, b[0].x, acc[i][0]);
      acc[i][1] = fmaf(a[i].x, b[0].y, acc[i][1]);
      acc[i][2] = fmaf(a[i].x, b[0].z, acc[i][2]);
      acc[i][3] = fmaf(a[i].x, b[0].w, acc[i][3]);
      acc[i][0] = fmaf(a[i].y, b[1].x, acc[i][0]);
      acc[i][1] = fmaf(a[i].y, b[1].y, acc[i][1]);
      acc[i][2] = fmaf(a[i].y, b[1].z, acc[i][2]);
      acc[i][3] = fmaf(a[i].y, b[1].w, acc[i][3]);
      acc[i][0] = fmaf(a[i].z, b[2].x, acc[i][0]);
      acc[i][1] = fmaf(a[i].z, b[2].y, acc[i][1]);
      acc[i][2] = fmaf(a[i].z, b[2].z, acc[i][2]);
      acc[i][3] = fmaf(a[i].z, b[2].w, acc[i][3]);
      acc[i][0] = fmaf(a[i].w, b[3].x, acc[i][0]);
      acc[i][1] = fmaf(a[i].w, b[3].y, acc[i][1]);
      acc[i][2] = fmaf(a[i].w, b[3].z, acc[i][2]);
      acc[i][3] = fmaf(a[i].w, b[3].w, acc[i][3]);
    }
  }

#pragma unroll
  for (int i = 0; i < 4; ++i) {
    int row = row0 + r0 + i;
    if (row < N) {
      float di = dinv[row];
      __half2 p01 = __floats2half2_rn(acc[i][0] * di, acc[i][1] * di);
      __half2 p23 = __floats2half2_rn(acc[i][2] * di, acc[i][3] * di);
      union { __half2 h2[2]; uint2 u; } cvt;
      cvt.h2[0] = p01; cvt.h2[1] = p23;
      *reinterpret_cast<uint2*>(O + (size_t)row * COLS + c0) = cvt.u;
    }
  }
}

// ========== layer-2 GEMM (scalar-A form; K=64, COLS=32) ==========

template <int ROWS, int COLS, int K>
__global__ __launch_bounds__(256) void gemm_kernel(const float* __restrict__ X,
                                                   const float* __restrict__ W,
                                                   const float* __restrict__ dinv,
                                                   __half* __restrict__ O, int N) {
  __shared__ float xs[ROWS][K + 4];
  __shared__ float ws[K][COLS];
  const int t = threadIdx.x;
  const int row0 = blockIdx.x * ROWS;

  constexpr int WV = K * COLS / 4;
  for (int i = t; i < WV; i += 256) {
    float4 v = reinterpret_cast<const float4*>(W)[i];
    int base = i * 4;
    int k = base / COLS, c = base % COLS;
    ws[k][c] = v.x; ws[k][c + 1] = v.y; ws[k][c + 2] = v.z; ws[k][c + 3] = v.w;
  }
  constexpr int XV = ROWS * K / 4;
  for (int i = t; i < XV; i += 256) {
    int base = i * 4;
    int r = base / K, k = base % K;
    int row = row0 + r;
    float4 v = make_float4(0.f, 0.f, 0.f, 0.f);
    if (row < N) v = reinterpret_cast<const float4*>(X + (size_t)row * K)[k >> 2];
    *reinterpret_cast<float4*>(&xs[r][k]) = v;
  }
  __syncthreads();

  constexpr int TC = COLS / 4;
  const int tc = t % TC, tr = t / TC;
  const int c0 = tc * 4, r0 = tr * 4;
  float acc[4][4] = {{0.f}};

#pragma unroll 8
  for (int k = 0; k < K; ++k) {
    float a0 = xs[r0 + 0][k];
    float a1 = xs[r0 + 1][k];
    float a2 = xs[r0 + 2][k];
    float a3 = xs[r0 + 3][k];
    float4 b = *reinterpret_cast<const float4*>(&ws[k][c0]);
    acc[0][0] = fmaf(a0, b.x, acc[0][0]); acc[0][1] = fmaf(a0, b.y, acc[0][1]);
    acc[0][2] = fmaf(a0, b.z, acc[0][2]); acc[0][3] = fmaf(a0, b.w, acc[0][3]);
    acc[1][0] = fmaf(a1, b.x, acc[1][0]); acc[1][1] = fmaf(a1, b.y, acc[1][1]);
    acc[1][2] = fmaf(a1, b.z, acc[1][2]); acc[1][3] = fmaf(a1, b.w, acc[1][3]);
    acc[2][0] = fmaf(a2, b.x, acc[2][0]); acc[2][1] = fmaf(a2, b.y, acc[2][1]);
    acc[2][2] = fmaf(a2, b.z, acc[2][2]); acc[2][3] = fmaf(a2, b.w, acc[2][3]);
    acc[3][0] = fmaf(a3, b.x, acc[3][0]); acc[3][1] = fmaf(a3, b.y, acc[3][1]);
    acc[3][2] = fmaf(a3, b.z, acc[3][2]); acc[3][3] = fmaf(a3, b.w, acc[3][3]);
  }

#pragma unroll
  for (int i = 0; i < 4; ++i) {
    int row = row0 + r0 + i;
    if (row < N) {
      float di = dinv[row];
      __half2 p01 = __floats2half2_rn(acc[i][0] * di, acc[i][1] * di);
      __half2 p23 = __floats2half2_rn(acc[i][2] * di, acc[i][3] * di);
      union { __half2 h2[2]; uint2 u; } cvt;
      cvt.h2[0] = p01; cvt.h2[1] = p23;
      *reinterpret_cast<uint2*>(O + (size_t)row * COLS + c0) = cvt.u;
    }
  }
}

// ================= CSR gather aggregation (fused epilogue) =================
// g rows are fp16, pre-scaled by dinv[src]; lane loads uint2 = 4 halves.

// FDIM=64: 16 lanes/edge, 4 edges per wave-iteration, 4x unroll (16 loads in flight).
__global__ __launch_bounds__(256) void gather64_kernel(const int* __restrict__ rowptr,
                                                       const int* __restrict__ ssrc,
                                                       const float* __restrict__ dinv,
                                                       const uint2* __restrict__ g,
                                                       const float4* __restrict__ bias,
                                                       float4* __restrict__ outb, int N) {
  int gid = (blockIdx.x * 256 + threadIdx.x) >> 6;
  int lane = threadIdx.x & 63;
  int col = lane & 15, sub = lane >> 4;
  if (gid >= N) return;
  int beg = rowptr[gid], end = rowptr[gid + 1];
  float4 a0 = {0.f, 0.f, 0.f, 0.f}, a1 = a0, a2 = a0, a3 = a0;
  int i = beg + sub;
  for (; i + 12 < end; i += 16) {
    int s0 = ssrc[i + 0];
    int s1 = ssrc[i + 4];
    int s2 = ssrc[i + 8];
    int s3 = ssrc[i + 12];
    uint2 v0 = g[(size_t)s0 * 16 + col];
    uint2 v1 = g[(size_t)s1 * 16 + col];
    uint2 v2 = g[(size_t)s2 * 16 + col];
    uint2 v3 = g[(size_t)s3 * 16 + col];
    float2 f;
    f = __half22float2(*(__half2*)&v0.x); a0.x += f.x; a0.y += f.y;
    f = __half22float2(*(__half2*)&v0.y); a0.z += f.x; a0.w += f.y;
    f = __half22float2(*(__half2*)&v1.x); a1.x += f.x; a1.y += f.y;
    f = __half22float2(*(__half2*)&v1.y); a1.z += f.x; a1.w += f.y;
    f = __half22float2(*(__half2*)&v2.x); a2.x += f.x; a2.y += f.y;
    f = __half22float2(*(__half2*)&v2.y); a2.z += f.x; a2.w += f.y;
    f = __half22float2(*(__half2*)&v3.x); a3.x += f.x; a3.y += f.y;
    f = __half22float2(*(__half2*)&v3.y); a3.z += f.x; a3.w += f.y;
  }
  for (; i < end; i += 4) {
    uint2 v = g[(size_t)ssrc[i] * 16 + col];
    float2 f;
    f = __half22float2(*(__half2*)&v.x); a0.x += f.x; a0.y += f.y;
    f = __half22float2(*(__half2*)&v.y); a0.z += f.x; a0.w += f.y;
  }
  float4 acc;
  acc.x = (a0.x + a1.x) + (a2.x + a3.x);
  acc.y = (a0.y + a1.y) + (a2.y + a3.y);
  acc.z = (a0.z + a1.z) + (a2.z + a3.z);
  acc.w = (a0.w + a1.w) + (a2.w + a3.w);
  acc.x += __shfl_xor(acc.x, 16, 64); acc.y += __shfl_xor(acc.y, 16, 64);
  acc.z += __shfl_xor(acc.z, 16, 64); acc.w += __shfl_xor(acc.w, 16, 64);
  acc.x += __shfl_xor(acc.x, 32, 64); acc.y += __shfl_xor(acc.y, 32, 64);
  acc.z += __shfl_xor(acc.z, 32, 64); acc.w += __shfl_xor(acc.w, 32, 64);
  if (sub == 0) {
    uint2 vs = g[(size_t)gid * 16 + col];
    float2 g01 = __half22float2(*(__half2*)&vs.x);
    float2 g23 = __half22float2(*(__half2*)&vs.y);
    float di = dinv[gid];
    float4 bb = bias[col];
    float4 o;
    o.x = fmaxf(fmaf(di, acc.x + g01.x, bb.x), 0.f);
    o.y = fmaxf(fmaf(di, acc.y + g01.y, bb.y), 0.f);
    o.z = fmaxf(fmaf(di, acc.z + g23.x, bb.z), 0.f);
    o.w = fmaxf(fmaf(di, acc.w + g23.y, bb.w), 0.f);
    outb[(size_t)gid * 16 + col] = o;
  }
}

// FDIM=32: 8 lanes/edge, 8 edges per wave-iteration, 2x unroll (16 loads in flight).
__global__ __launch_bounds__(256) void gather32_kernel(const int* __restrict__ rowptr,
                                                       const int* __restrict__ ssrc,
                                                       const float* __restrict__ dinv,
                                                       const uint2* __restrict__ g,
                                                       const float4* __restrict__ bias,
                                                       float4* __restrict__ outb, int N) {
  int gid = (blockIdx.x * 256 + threadIdx.x) >> 6;
  int lane = threadIdx.x & 63;
  int col = lane & 7, sub = lane >> 3;
  if (gid >= N) return;
  int beg = rowptr[gid], end = rowptr[gid + 1];
  float4 a0 = {0.f, 0.f, 0.f, 0.f}, a1 = a0;
  int i = beg + sub;
  for (; i + 8 < end; i += 16) {
    int s0 = ssrc[i + 0];
    int s1 = ssrc[i + 8];
    uint2 v0 = g[(size_t)s0 * 8 + col];
    uint2 v1 = g[(size_t)s1 * 8 + col];
    float2 f;
    f = __half22float2(*(__half2*)&v0.x); a0.x += f.x; a0.y += f.y;
    f = __half22float2(*(__half2*)&v0.y); a0.z += f.x; a0.w += f.y;
    f = __half22float2(*(__half2*)&v1.x); a1.x += f.x; a1.y += f.y;
    f = __half22float2(*(__half2*)&v1.y); a1.z += f.x; a1.w += f.y;
  }
  for (; i < end; i += 8) {
    uint2 v = g[(size_t)ssrc[i] * 8 + col];
    float2 f;
    f = __half22float2(*(__half2*)&v.x); a0.x += f.x; a0.y += f.y;
    f = __half22float2(*(__half2*)&v.y); a0.z += f.x; a0.w += f.y;
  }
  float4 acc;
  acc.x = a0.x + a1.x; acc.y = a0.y + a1.y;
  acc.z = a0.z + a1.z; acc.w = a0.w + a1.w;
  acc.x += __shfl_xor(acc.x, 8, 64);  acc.y += __shfl_xor(acc.y, 8, 64);
  acc.z += __shfl_xor(acc.z, 8, 64);  acc.w += __shfl_xor(acc.w, 8, 64);
  acc.x += __shfl_xor(acc.x, 16, 64); acc.y += __shfl_xor(acc.y, 16, 64);
  acc.z += __shfl_xor(acc.z, 16, 64); acc.w += __shfl_xor(acc.w, 16, 64);
  acc.x += __shfl_xor(acc.x, 32, 64); acc.y += __shfl_xor(acc.y, 32, 64);
  acc.z += __shfl_xor(acc.z, 32, 64); acc.w += __shfl_xor(acc.w, 32, 64);
  if (sub == 0) {
    uint2 vs = g[(size_t)gid * 8 + col];
    float2 g01 = __half22float2(*(__half2*)&vs.x);
    float2 g23 = __half22float2(*(__half2*)&vs.y);
    float di = dinv[gid];
    float4 bb = bias[col];
    float4 o;
    o.x = fmaf(di, acc.x + g01.x, bb.x);
    o.y = fmaf(di, acc.y + g01.y, bb.y);
    o.z = fmaf(di, acc.z + g23.x, bb.z);
    o.w = fmaf(di, acc.w + g23.y, bb.w);
    outb[(size_t)gid * 8 + col] = o;
  }
}

// ================= launch =================

extern "C" void kernel_launch(void* const* d_in, const int* in_sizes, int n_in,
                              void* d_out, int out_size, void* d_ws, size_t ws_size,
                              hipStream_t stream) {
  const float* x  = (const float*)d_in[0];
  const int*   ei = (const int*)d_in[1];
  const float* W1 = (const float*)d_in[2];
  const float* b1 = (const float*)d_in[3];
  const float* W2 = (const float*)d_in[4];
  const float* b2 = (const float*)d_in[5];
  float* out = (float*)d_out;

  const int H = in_sizes[3];            // 64
  const int F = in_sizes[2] / H;        // 128
  const int N = in_sizes[0] / F;        // 100000
  const int E = in_sizes[1] / 2;        // 1600000
  const int* src = ei;
  const int* dst = ei + E;

  const int nblk = (N + 1023) / 1024;

  char* w = (char*)d_ws;
  auto alloc = [&](size_t bytes) { char* p = w; w += (bytes + 255) & ~(size_t)255; return p; };
  int*    ideg   = (int*)alloc((size_t)N * 4);
  int*    rowptr = (int*)alloc((size_t)(N + 1) * 4);
  int*    bsum   = (int*)alloc(256 * 4);
  int*    boff   = (int*)alloc(256 * 4);
  int*    posbuf = (int*)alloc((size_t)E * 4);
  int*    ssrc   = (int*)alloc((size_t)E * 4);
  float*  dinv   = (float*)alloc((size_t)N * 4);
  __half* g1     = (__half*)alloc((size_t)N * 64 * 2);
  float*  buf1   = (float*)alloc((size_t)N * 64 * 4);
  __half* g2     = (__half*)alloc((size_t)N * 32 * 2);

  hipMemsetAsync(ideg, 0, (size_t)N * 4, stream);

  // CSR build
  degpos_kernel<<<((E + 1) / 2 + 255) / 256, 256, 0, stream>>>(dst, ideg, posbuf, E);
  scanA_kernel<<<nblk, 256, 0, stream>>>(ideg, rowptr + 1, bsum, N);
  scanB_kernel<<<1, 256, 0, stream>>>(bsum, boff, nblk);
  scanC_kernel<<<(N + 255) / 256, 256, 0, stream>>>(rowptr, boff, N);
  dinv_kernel<<<(N + 255) / 256, 256, 0, stream>>>(ideg, dinv, N);
  fillpos_kernel<<<((E + 1) / 2 + 255) / 256, 256, 0, stream>>>(src, dst, posbuf, rowptr, ssrc, E);

  // layer 1: g1 = dinv .* (x @ W1)   (fp16)
  gemmk4_kernel<64, 64, 128><<<(N + 63) / 64, 256, 0, stream>>>(x, W1, dinv, g1, N);
  gather64_kernel<<<(N + 3) / 4, 256, 0, stream>>>(rowptr, ssrc, dinv,
      (const uint2*)g1, (const float4*)b1, (float4*)buf1, N);

  // layer 2: g2 = dinv .* (r1 @ W2)  (fp16)
  gemm_kernel<128, 32, 64><<<(N + 127) / 128, 256, 0, stream>>>(buf1, W2, dinv, g2, N);
  gather32_kernel<<<(N + 3) / 4, 256, 0, stream>>>(rowptr, ssrc, dinv,
      (const uint2*)g2, (const float4*)b2, (float4*)out, N);
}

// Round 6
// 188.686 us; speedup vs baseline: 11.1596x; 1.3172x over previous
//
#include <hip/hip_runtime.h>
#include <hip/hip_fp16.h>

#define B_HIST 512   // blocks in hist/scatter phases (must match both)
#define SHIFT  9     // coarse bucket = dst >> 9 (512 nodes/bucket); NB <= 256 for N <= 131072

// ================= CSR build: two-level counting sort, LDS atomics only =================

// P1: per-block 256-bin coarse histogram -> histT[bin*B_HIST + block]
__global__ __launch_bounds__(256) void p1_hist(const int* __restrict__ dst,
                                               int* __restrict__ histT, int E) {
  __shared__ int h[256];
  const int t = threadIdx.x;
  h[t] = 0;
  __syncthreads();
  const int epb = (E + B_HIST - 1) / B_HIST;
  const int beg = blockIdx.x * epb;
  const int end = min(beg + epb, E);
  for (int e = beg + t; e < end; e += 256)
    atomicAdd(&h[dst[e] >> SHIFT], 1);          // LDS atomic
  __syncthreads();
  histT[t * B_HIST + blockIdx.x] = h[t];
}

// P2a: per-bin exclusive scan down the block column; colsum -> bsum[bin]
__global__ __launch_bounds__(256) void p2a_colscan(int* __restrict__ histT,
                                                   int* __restrict__ bsum) {
  __shared__ int sdata[256];
  const int bin = blockIdx.x, t = threadIdx.x;
  const int i0 = bin * B_HIST + 2 * t;
  int c0 = histT[i0], c1 = histT[i0 + 1];
  int s = c0 + c1;
  sdata[t] = s;
  __syncthreads();
  for (int off = 1; off < 256; off <<= 1) {
    int x = 0;
    if (t >= off) x = sdata[t - off];
    __syncthreads();
    if (t >= off) sdata[t] += x;
    __syncthreads();
  }
  int excl = sdata[t] - s;
  histT[i0] = excl;
  histT[i0 + 1] = excl + c0;
  if (t == 255) bsum[bin] = sdata[255];
}

// P2b: exclusive scan of 256 bucket totals -> colstart[257] (colstart[256] = E)
__global__ __launch_bounds__(256) void p2b_scan(const int* __restrict__ bsum,
                                                int* __restrict__ colstart) {
  __shared__ int sdata[256];
  const int t = threadIdx.x;
  int v = bsum[t];
  sdata[t] = v;
  __syncthreads();
  for (int off = 1; off < 256; off <<= 1) {
    int x = 0;
    if (t >= off) x = sdata[t - off];
    __syncthreads();
    if (t >= off) sdata[t] += x;
    __syncthreads();
  }
  colstart[t] = sdata[t] - v;
  if (t == 255) colstart[256] = sdata[255];
}

// P3: atomic-free global scatter into coarse buckets; pack (dstLow<<17)|src
__global__ __launch_bounds__(256) void p3_scatter(const int* __restrict__ src,
                                                  const int* __restrict__ dst,
                                                  const int* __restrict__ histT,
                                                  const int* __restrict__ colstart,
                                                  int* __restrict__ pbuf, int E) {
  __shared__ int cur[256];
  const int t = threadIdx.x;
  cur[t] = colstart[t] + histT[t * B_HIST + blockIdx.x];
  __syncthreads();
  const int epb = (E + B_HIST - 1) / B_HIST;
  const int beg = blockIdx.x * epb;
  const int end = min(beg + epb, E);
  for (int e = beg + t; e < end; e += 256) {
    int d = dst[e];
    int s = src[e];
    int pos = atomicAdd(&cur[d >> SHIFT], 1);   // LDS atomic
    pbuf[pos] = ((d & 511) << 17) | s;
  }
}

// P4: per-bucket fine counting sort -> rowptr, dinv, ssrc (all LDS atomics)
__global__ __launch_bounds__(256) void p4_fine(const int* __restrict__ pbuf,
                                               const int* __restrict__ colstart,
                                               int* __restrict__ rowptr,
                                               float* __restrict__ dinv,
                                               int* __restrict__ ssrc, int N, int NB) {
  __shared__ int cnt[512];
  __shared__ int sdata[256];
  __shared__ int cur[512];
  const int b = blockIdx.x, t = threadIdx.x;
  const int base = colstart[b], endp = colstart[b + 1];
  cnt[2 * t] = 0; cnt[2 * t + 1] = 0;
  __syncthreads();
  for (int i = base + t; i < endp; i += 256)
    atomicAdd(&cnt[pbuf[i] >> 17], 1);
  __syncthreads();
  int c0 = cnt[2 * t], c1 = cnt[2 * t + 1];
  int s = c0 + c1;
  sdata[t] = s;
  __syncthreads();
  for (int off = 1; off < 256; off <<= 1) {
    int x = 0;
    if (t >= off) x = sdata[t - off];
    __syncthreads();
    if (t >= off) sdata[t] += x;
    __syncthreads();
  }
  int excl = sdata[t] - s;
  int e0 = base + excl, e1 = base + excl + c0;
  cur[2 * t] = e0;
  cur[2 * t + 1] = e1;
  int node0 = (b << SHIFT) + 2 * t;
  if (node0 < N) {
    rowptr[node0] = e0;
    dinv[node0] = rsqrtf((float)c0 + 1.0f);
  }
  if (node0 + 1 < N) {
    rowptr[node0 + 1] = e1;
    dinv[node0 + 1] = rsqrtf((float)c1 + 1.0f);
  }
  if (b == NB - 1 && t == 0) rowptr[N] = endp;
  __syncthreads();
  for (int i = base + t; i < endp; i += 256) {
    int p = pbuf[i];
    int pos = atomicAdd(&cur[p >> 17], 1);      // LDS atomic
    ssrc[pos] = p & 0x1FFFF;
  }
}

// ========== layer-1 GEMM (K4 form, FMA-bound): G = dinv .* (X @ W), fp16 out ==========

template <int ROWS, int COLS, int K>
__global__ __launch_bounds__(256) void gemmk4_kernel(const float* __restrict__ X,
                                                     const float* __restrict__ W,
                                                     const float* __restrict__ dinv,
                                                     __half* __restrict__ O, int N) {
  __shared__ float xs[ROWS][K + 4];
  __shared__ float ws[K][COLS];
  const int t = threadIdx.x;
  const int row0 = blockIdx.x * ROWS;

  constexpr int WV = K * COLS / 4;
  for (int i = t; i < WV; i += 256) {
    float4 v = reinterpret_cast<const float4*>(W)[i];
    int base = i * 4;
    int k = base / COLS, c = base % COLS;
    ws[k][c] = v.x; ws[k][c + 1] = v.y; ws[k][c + 2] = v.z; ws[k][c + 3] = v.w;
  }
  constexpr int XV = ROWS * K / 4;
  for (int i = t; i < XV; i += 256) {
    int base = i * 4;
    int r = base / K, k = base % K;
    int row = row0 + r;
    float4 v = make_float4(0.f, 0.f, 0.f, 0.f);
    if (row < N) v = reinterpret_cast<const float4*>(X + (size_t)row * K)[k >> 2];
    *reinterpret_cast<float4*>(&xs[r][k]) = v;
  }
  __syncthreads();

  constexpr int TC = COLS / 4;
  const int tc = t % TC, tr = t / TC;
  const int c0 = tc * 4, r0 = tr * 4;
  float acc[4][4] = {{0.f}};

  for (int k = 0; k < K; k += 4) {
    float4 a[4], b[4];
#pragma unroll
    for (int i = 0; i < 4; ++i)
      a[i] = *reinterpret_cast<const float4*>(&xs[r0 + i][k]);
#pragma unroll
    for (int j = 0; j < 4; ++j)
      b[j] = *reinterpret_cast<const float4*>(&ws[k + j][c0]);
#pragma unroll
    for (int i = 0; i < 4; ++i) {
      acc[i][0] = fmaf(a[i].x, b[0].x, acc[i][0]);
      acc[i][1] = fmaf(a[i].x, b[0].y, acc[i][1]);
      acc[i][2] = fmaf(a[i].x, b[0].z, acc[i][2]);
      acc[i][3] = fmaf(a[i].x, b[0].w, acc[i][3]);
      acc[i][0] = fmaf(a[i].y, b[1].x, acc[i][0]);
      acc[i][1] = fmaf(a[i].y, b[1].y, acc[i][1]);
      acc[i][2] = fmaf(a[i].y, b[1].z, acc[i][2]);
      acc[i][3] = fmaf(a[i].y, b[1].w, acc[i][3]);
      acc[i][0] = fmaf(a[i].z, b[2].x, acc[i][0]);
      acc[i][1] = fmaf(a[i].z, b[2].y, acc[i][1]);
      acc[i][2] = fmaf(a[i].z, b[2].z, acc[i][2]);
      acc[i][3] = fmaf(a[i].z, b[2].w, acc[i][3]);
      acc[i][0] = fmaf(a[i].w, b[3].x, acc[i][0]);
      acc[i][1] = fmaf(a[i].w, b[3].y, acc[i][1]);
      acc[i][2] = fmaf(a[i].w, b[3].z, acc[i][2]);
      acc[i][3] = fmaf(a[i].w, b[3].w, acc[i][3]);
    }
  }

#pragma unroll
  for (int i = 0; i < 4; ++i) {
    int row = row0 + r0 + i;
    if (row < N) {
      float di = dinv[row];
      __half2 p01 = __floats2half2_rn(acc[i][0] * di, acc[i][1] * di);
      __half2 p23 = __floats2half2_rn(acc[i][2] * di, acc[i][3] * di);
      union { __half2 h2[2]; uint2 u; } cvt;
      cvt.h2[0] = p01; cvt.h2[1] = p23;
      *reinterpret_cast<uint2*>(O + (size_t)row * COLS + c0) = cvt.u;
    }
  }
}

// ========== layer-2 GEMM (scalar-A form; K=64, COLS=32) ==========

template <int ROWS, int COLS, int K>
__global__ __launch_bounds__(256) void gemm_kernel(const float* __restrict__ X,
                                                   const float* __restrict__ W,
                                                   const float* __restrict__ dinv,
                                                   __half* __restrict__ O, int N) {
  __shared__ float xs[ROWS][K + 4];
  __shared__ float ws[K][COLS];
  const int t = threadIdx.x;
  const int row0 = blockIdx.x * ROWS;

  constexpr int WV = K * COLS / 4;
  for (int i = t; i < WV; i += 256) {
    float4 v = reinterpret_cast<const float4*>(W)[i];
    int base = i * 4;
    int k = base / COLS, c = base % COLS;
    ws[k][c] = v.x; ws[k][c + 1] = v.y; ws[k][c + 2] = v.z; ws[k][c + 3] = v.w;
  }
  constexpr int XV = ROWS * K / 4;
  for (int i = t; i < XV; i += 256) {
    int base = i * 4;
    int r = base / K, k = base % K;
    int row = row0 + r;
    float4 v = make_float4(0.f, 0.f, 0.f, 0.f);
    if (row < N) v = reinterpret_cast<const float4*>(X + (size_t)row * K)[k >> 2];
    *reinterpret_cast<float4*>(&xs[r][k]) = v;
  }
  __syncthreads();

  constexpr int TC = COLS / 4;
  const int tc = t % TC, tr = t / TC;
  const int c0 = tc * 4, r0 = tr * 4;
  float acc[4][4] = {{0.f}};

#pragma unroll 8
  for (int k = 0; k < K; ++k) {
    float a0 = xs[r0 + 0][k];
    float a1 = xs[r0 + 1][k];
    float a2 = xs[r0 + 2][k];
    float a3 = xs[r0 + 3][k];
    float4 b = *reinterpret_cast<const float4*>(&ws[k][c0]);
    acc[0][0] = fmaf(a0, b.x, acc[0][0]); acc[0][1] = fmaf(a0, b.y, acc[0][1]);
    acc[0][2] = fmaf(a0, b.z, acc[0][2]); acc[0][3] = fmaf(a0, b.w, acc[0][3]);
    acc[1][0] = fmaf(a1, b.x, acc[1][0]); acc[1][1] = fmaf(a1, b.y, acc[1][1]);
    acc[1][2] = fmaf(a1, b.z, acc[1][2]); acc[1][3] = fmaf(a1, b.w, acc[1][3]);
    acc[2][0] = fmaf(a2, b.x, acc[2][0]); acc[2][1] = fmaf(a2, b.y, acc[2][1]);
    acc[2][2] = fmaf(a2, b.z, acc[2][2]); acc[2][3] = fmaf(a2, b.w, acc[2][3]);
    acc[3][0] = fmaf(a3, b.x, acc[3][0]); acc[3][1] = fmaf(a3, b.y, acc[3][1]);
    acc[3][2] = fmaf(a3, b.z, acc[3][2]); acc[3][3] = fmaf(a3, b.w, acc[3][3]);
  }

#pragma unroll
  for (int i = 0; i < 4; ++i) {
    int row = row0 + r0 + i;
    if (row < N) {
      float di = dinv[row];
      __half2 p01 = __floats2half2_rn(acc[i][0] * di, acc[i][1] * di);
      __half2 p23 = __floats2half2_rn(acc[i][2] * di, acc[i][3] * di);
      union { __half2 h2[2]; uint2 u; } cvt;
      cvt.h2[0] = p01; cvt.h2[1] = p23;
      *reinterpret_cast<uint2*>(O + (size_t)row * COLS + c0) = cvt.u;
    }
  }
}

// ================= CSR gather aggregation (fused epilogue) =================
// g rows are fp16, pre-scaled by dinv[src]; lane loads uint2 = 4 halves.

// FDIM=64: 16 lanes/edge, 4 edges per wave-iteration, 4x unroll (16 loads in flight).
__global__ __launch_bounds__(256) void gather64_kernel(const int* __restrict__ rowptr,
                                                       const int* __restrict__ ssrc,
                                                       const float* __restrict__ dinv,
                                                       const uint2* __restrict__ g,
                                                       const float4* __restrict__ bias,
                                                       float4* __restrict__ outb, int N) {
  int gid = (blockIdx.x * 256 + threadIdx.x) >> 6;
  int lane = threadIdx.x & 63;
  int col = lane & 15, sub = lane >> 4;
  if (gid >= N) return;
  int beg = rowptr[gid], end = rowptr[gid + 1];
  float4 a0 = {0.f, 0.f, 0.f, 0.f}, a1 = a0, a2 = a0, a3 = a0;
  int i = beg + sub;
  for (; i + 12 < end; i += 16) {
    int s0 = ssrc[i + 0];
    int s1 = ssrc[i + 4];
    int s2 = ssrc[i + 8];
    int s3 = ssrc[i + 12];
    uint2 v0 = g[(size_t)s0 * 16 + col];
    uint2 v1 = g[(size_t)s1 * 16 + col];
    uint2 v2 = g[(size_t)s2 * 16 + col];
    uint2 v3 = g[(size_t)s3 * 16 + col];
    float2 f;
    f = __half22float2(*(__half2*)&v0.x); a0.x += f.x; a0.y += f.y;
    f = __half22float2(*(__half2*)&v0.y); a0.z += f.x; a0.w += f.y;
    f = __half22float2(*(__half2*)&v1.x); a1.x += f.x; a1.y += f.y;
    f = __half22float2(*(__half2*)&v1.y); a1.z += f.x; a1.w += f.y;
    f = __half22float2(*(__half2*)&v2.x); a2.x += f.x; a2.y += f.y;
    f = __half22float2(*(__half2*)&v2.y); a2.z += f.x; a2.w += f.y;
    f = __half22float2(*(__half2*)&v3.x); a3.x += f.x; a3.y += f.y;
    f = __half22float2(*(__half2*)&v3.y); a3.z += f.x; a3.w += f.y;
  }
  for (; i < end; i += 4) {
    uint2 v = g[(size_t)ssrc[i] * 16 + col];
    float2 f;
    f = __half22float2(*(__half2*)&v.x); a0.x += f.x; a0.y += f.y;
    f = __half22float2(*(__half2*)&v.y); a0.z += f.x; a0.w += f.y;
  }
  float4 acc;
  acc.x = (a0.x + a1.x) + (a2.x + a3.x);
  acc.y = (a0.y + a1.y) + (a2.y + a3.y);
  acc.z = (a0.z + a1.z) + (a2.z + a3.z);
  acc.w = (a0.w + a1.w) + (a2.w + a3.w);
  acc.x += __shfl_xor(acc.x, 16, 64); acc.y += __shfl_xor(acc.y, 16, 64);
  acc.z += __shfl_xor(acc.z, 16, 64); acc.w += __shfl_xor(acc.w, 16, 64);
  acc.x += __shfl_xor(acc.x, 32, 64); acc.y += __shfl_xor(acc.y, 32, 64);
  acc.z += __shfl_xor(acc.z, 32, 64); acc.w += __shfl_xor(acc.w, 32, 64);
  if (sub == 0) {
    uint2 vs = g[(size_t)gid * 16 + col];
    float2 g01 = __half22float2(*(__half2*)&vs.x);
    float2 g23 = __half22float2(*(__half2*)&vs.y);
    float di = dinv[gid];
    float4 bb = bias[col];
    float4 o;
    o.x = fmaxf(fmaf(di, acc.x + g01.x, bb.x), 0.f);
    o.y = fmaxf(fmaf(di, acc.y + g01.y, bb.y), 0.f);
    o.z = fmaxf(fmaf(di, acc.z + g23.x, bb.z), 0.f);
    o.w = fmaxf(fmaf(di, acc.w + g23.y, bb.w), 0.f);
    outb[(size_t)gid * 16 + col] = o;
  }
}

// FDIM=32: 8 lanes/edge, 8 edges per wave-iteration, 2x unroll (16 loads in flight).
__global__ __launch_bounds__(256) void gather32_kernel(const int* __restrict__ rowptr,
                                                       const int* __restrict__ ssrc,
                                                       const float* __restrict__ dinv,
                                                       const uint2* __restrict__ g,
                                                       const float4* __restrict__ bias,
                                                       float4* __restrict__ outb, int N) {
  int gid = (blockIdx.x * 256 + threadIdx.x) >> 6;
  int lane = threadIdx.x & 63;
  int col = lane & 7, sub = lane >> 3;
  if (gid >= N) return;
  int beg = rowptr[gid], end = rowptr[gid + 1];
  float4 a0 = {0.f, 0.f, 0.f, 0.f}, a1 = a0;
  int i = beg + sub;
  for (; i + 8 < end; i += 16) {
    int s0 = ssrc[i + 0];
    int s1 = ssrc[i + 8];
    uint2 v0 = g[(size_t)s0 * 8 + col];
    uint2 v1 = g[(size_t)s1 * 8 + col];
    float2 f;
    f = __half22float2(*(__half2*)&v0.x); a0.x += f.x; a0.y += f.y;
    f = __half22float2(*(__half2*)&v0.y); a0.z += f.x; a0.w += f.y;
    f = __half22float2(*(__half2*)&v1.x); a1.x += f.x; a1.y += f.y;
    f = __half22float2(*(__half2*)&v1.y); a1.z += f.x; a1.w += f.y;
  }
  for (; i < end; i += 8) {
    uint2 v = g[(size_t)ssrc[i] * 8 + col];
    float2 f;
    f = __half22float2(*(__half2*)&v.x); a0.x += f.x; a0.y += f.y;
    f = __half22float2(*(__half2*)&v.y); a0.z += f.x; a0.w += f.y;
  }
  float4 acc;
  acc.x = a0.x + a1.x; acc.y = a0.y + a1.y;
  acc.z = a0.z + a1.z; acc.w = a0.w + a1.w;
  acc.x += __shfl_xor(acc.x, 8, 64);  acc.y += __shfl_xor(acc.y, 8, 64);
  acc.z += __shfl_xor(acc.z, 8, 64);  acc.w += __shfl_xor(acc.w, 8, 64);
  acc.x += __shfl_xor(acc.x, 16, 64); acc.y += __shfl_xor(acc.y, 16, 64);
  acc.z += __shfl_xor(acc.z, 16, 64); acc.w += __shfl_xor(acc.w, 16, 64);
  acc.x += __shfl_xor(acc.x, 32, 64); acc.y += __shfl_xor(acc.y, 32, 64);
  acc.z += __shfl_xor(acc.z, 32, 64); acc.w += __shfl_xor(acc.w, 32, 64);
  if (sub == 0) {
    uint2 vs = g[(size_t)gid * 8 + col];
    float2 g01 = __half22float2(*(__half2*)&vs.x);
    float2 g23 = __half22float2(*(__half2*)&vs.y);
    float di = dinv[gid];
    float4 bb = bias[col];
    float4 o;
    o.x = fmaf(di, acc.x + g01.x, bb.x);
    o.y = fmaf(di, acc.y + g01.y, bb.y);
    o.z = fmaf(di, acc.z + g23.x, bb.z);
    o.w = fmaf(di, acc.w + g23.y, bb.w);
    outb[(size_t)gid * 8 + col] = o;
  }
}

// ================= launch =================

extern "C" void kernel_launch(void* const* d_in, const int* in_sizes, int n_in,
                              void* d_out, int out_size, void* d_ws, size_t ws_size,
                              hipStream_t stream) {
  const float* x  = (const float*)d_in[0];
  const int*   ei = (const int*)d_in[1];
  const float* W1 = (const float*)d_in[2];
  const float* b1 = (const float*)d_in[3];
  const float* W2 = (const float*)d_in[4];
  const float* b2 = (const float*)d_in[5];
  float* out = (float*)d_out;

  const int H = in_sizes[3];            // 64
  const int F = in_sizes[2] / H;        // 128
  const int N = in_sizes[0] / F;        // 100000
  const int E = in_sizes[1] / 2;        // 1600000
  const int* src = ei;
  const int* dst = ei + E;
  const int NB = (N + 511) >> SHIFT;    // coarse buckets (196 for N=100k)

  char* w = (char*)d_ws;
  auto alloc = [&](size_t bytes) { char* p = w; w += (bytes + 255) & ~(size_t)255; return p; };
  int*    histT    = (int*)alloc((size_t)256 * B_HIST * 4);
  int*    bsum     = (int*)alloc(256 * 4);
  int*    colstart = (int*)alloc(257 * 4);
  int*    pbuf     = (int*)alloc((size_t)E * 4);
  int*    ssrc     = (int*)alloc((size_t)E * 4);
  int*    rowptr   = (int*)alloc((size_t)(N + 1) * 4);
  float*  dinv     = (float*)alloc((size_t)N * 4);
  __half* g1       = (__half*)alloc((size_t)N * 64 * 2);
  float*  buf1     = (float*)alloc((size_t)N * 64 * 4);
  __half* g2       = (__half*)alloc((size_t)N * 32 * 2);

  // CSR build (no global atomics)
  p1_hist<<<B_HIST, 256, 0, stream>>>(dst, histT, E);
  p2a_colscan<<<256, 256, 0, stream>>>(histT, bsum);
  p2b_scan<<<1, 256, 0, stream>>>(bsum, colstart);
  p3_scatter<<<B_HIST, 256, 0, stream>>>(src, dst, histT, colstart, pbuf, E);
  p4_fine<<<NB, 256, 0, stream>>>(pbuf, colstart, rowptr, dinv, ssrc, N, NB);

  // layer 1: g1 = dinv .* (x @ W1)   (fp16)
  gemmk4_kernel<64, 64, 128><<<(N + 63) / 64, 256, 0, stream>>>(x, W1, dinv, g1, N);
  gather64_kernel<<<(N + 3) / 4, 256, 0, stream>>>(rowptr, ssrc, dinv,
      (const uint2*)g1, (const float4*)b1, (float4*)buf1, N);

  // layer 2: g2 = dinv .* (r1 @ W2)  (fp16)
  gemm_kernel<128, 32, 64><<<(N + 127) / 128, 256, 0, stream>>>(buf1, W2, dinv, g2, N);
  gather32_kernel<<<(N + 3) / 4, 256, 0, stream>>>(rowptr, ssrc, dinv,
      (const uint2*)g2, (const float4*)b2, (float4*)out, N);
}

// Round 7
// 172.033 us; speedup vs baseline: 12.2399x; 1.0968x over previous
//
#include <hip/hip_runtime.h>
#include <hip/hip_fp16.h>

#define B_HIST 512   // blocks in hist/scatter phases (must match both)
#define SHIFT  9     // coarse bucket = dst >> 9 (512 nodes/bucket); NB <= 256 for N <= 131072

// ================= CSR build: two-level counting sort, LDS atomics only =================

// P1: per-block 256-bin coarse histogram -> histT[bin*B_HIST + block]
__global__ __launch_bounds__(256) void p1_hist(const int* __restrict__ dst,
                                               int* __restrict__ histT, int E) {
  __shared__ int h[256];
  const int t = threadIdx.x;
  h[t] = 0;
  __syncthreads();
  const int epb = (E + B_HIST - 1) / B_HIST;
  const int beg = blockIdx.x * epb;
  const int end = min(beg + epb, E);
  for (int e = beg + t; e < end; e += 256)
    atomicAdd(&h[dst[e] >> SHIFT], 1);          // LDS atomic
  __syncthreads();
  histT[t * B_HIST + blockIdx.x] = h[t];
}

// P2a: per-bin exclusive scan down the block column; colsum -> bsum[bin]
__global__ __launch_bounds__(256) void p2a_colscan(int* __restrict__ histT,
                                                   int* __restrict__ bsum) {
  __shared__ int sdata[256];
  const int bin = blockIdx.x, t = threadIdx.x;
  const int i0 = bin * B_HIST + 2 * t;
  int c0 = histT[i0], c1 = histT[i0 + 1];
  int s = c0 + c1;
  sdata[t] = s;
  __syncthreads();
  for (int off = 1; off < 256; off <<= 1) {
    int x = 0;
    if (t >= off) x = sdata[t - off];
    __syncthreads();
    if (t >= off) sdata[t] += x;
    __syncthreads();
  }
  int excl = sdata[t] - s;
  histT[i0] = excl;
  histT[i0 + 1] = excl + c0;
  if (t == 255) bsum[bin] = sdata[255];
}

// P2b: exclusive scan of 256 bucket totals -> colstart[257] (colstart[256] = E)
__global__ __launch_bounds__(256) void p2b_scan(const int* __restrict__ bsum,
                                                int* __restrict__ colstart) {
  __shared__ int sdata[256];
  const int t = threadIdx.x;
  int v = bsum[t];
  sdata[t] = v;
  __syncthreads();
  for (int off = 1; off < 256; off <<= 1) {
    int x = 0;
    if (t >= off) x = sdata[t - off];
    __syncthreads();
    if (t >= off) sdata[t] += x;
    __syncthreads();
  }
  colstart[t] = sdata[t] - v;
  if (t == 255) colstart[256] = sdata[255];
}

// P3: atomic-free global scatter into coarse buckets; pack (dstLow<<17)|src
__global__ __launch_bounds__(256) void p3_scatter(const int* __restrict__ src,
                                                  const int* __restrict__ dst,
                                                  const int* __restrict__ histT,
                                                  const int* __restrict__ colstart,
                                                  int* __restrict__ pbuf, int E) {
  __shared__ int cur[256];
  const int t = threadIdx.x;
  cur[t] = colstart[t] + histT[t * B_HIST + blockIdx.x];
  __syncthreads();
  const int epb = (E + B_HIST - 1) / B_HIST;
  const int beg = blockIdx.x * epb;
  const int end = min(beg + epb, E);
  for (int e = beg + t; e < end; e += 256) {
    int d = dst[e];
    int s = src[e];
    int pos = atomicAdd(&cur[d >> SHIFT], 1);   // LDS atomic
    pbuf[pos] = ((d & 511) << 17) | s;
  }
}

// P4: per-bucket fine counting sort -> rowptr, dinv, ssrc (all LDS atomics)
__global__ __launch_bounds__(256) void p4_fine(const int* __restrict__ pbuf,
                                               const int* __restrict__ colstart,
                                               int* __restrict__ rowptr,
                                               float* __restrict__ dinv,
                                               int* __restrict__ ssrc, int N, int NB) {
  __shared__ int cnt[512];
  __shared__ int sdata[256];
  __shared__ int cur[512];
  const int b = blockIdx.x, t = threadIdx.x;
  const int base = colstart[b], endp = colstart[b + 1];
  cnt[2 * t] = 0; cnt[2 * t + 1] = 0;
  __syncthreads();
  for (int i = base + t; i < endp; i += 256)
    atomicAdd(&cnt[pbuf[i] >> 17], 1);
  __syncthreads();
  int c0 = cnt[2 * t], c1 = cnt[2 * t + 1];
  int s = c0 + c1;
  sdata[t] = s;
  __syncthreads();
  for (int off = 1; off < 256; off <<= 1) {
    int x = 0;
    if (t >= off) x = sdata[t - off];
    __syncthreads();
    if (t >= off) sdata[t] += x;
    __syncthreads();
  }
  int excl = sdata[t] - s;
  int e0 = base + excl, e1 = base + excl + c0;
  cur[2 * t] = e0;
  cur[2 * t + 1] = e1;
  int node0 = (b << SHIFT) + 2 * t;
  if (node0 < N) {
    rowptr[node0] = e0;
    dinv[node0] = rsqrtf((float)c0 + 1.0f);
  }
  if (node0 + 1 < N) {
    rowptr[node0 + 1] = e1;
    dinv[node0 + 1] = rsqrtf((float)c1 + 1.0f);
  }
  if (b == NB - 1 && t == 0) rowptr[N] = endp;
  __syncthreads();
  for (int i = base + t; i < endp; i += 256) {
    int p = pbuf[i];
    int pos = atomicAdd(&cur[p >> 17], 1);      // LDS atomic
    ssrc[pos] = p & 0x1FFFF;
  }
}

// ========== layer-1 GEMM (K4 form, FMA-bound): G = dinv .* (X @ W), fp16 out ==========

template <int ROWS, int COLS, int K>
__global__ __launch_bounds__(256) void gemmk4_kernel(const float* __restrict__ X,
                                                     const float* __restrict__ W,
                                                     const float* __restrict__ dinv,
                                                     __half* __restrict__ O, int N) {
  __shared__ float xs[ROWS][K + 4];
  __shared__ float ws[K][COLS];
  const int t = threadIdx.x;
  const int row0 = blockIdx.x * ROWS;

  constexpr int WV = K * COLS / 4;
  for (int i = t; i < WV; i += 256) {
    float4 v = reinterpret_cast<const float4*>(W)[i];
    int base = i * 4;
    int k = base / COLS, c = base % COLS;
    ws[k][c] = v.x; ws[k][c + 1] = v.y; ws[k][c + 2] = v.z; ws[k][c + 3] = v.w;
  }
  constexpr int XV = ROWS * K / 4;
  for (int i = t; i < XV; i += 256) {
    int base = i * 4;
    int r = base / K, k = base % K;
    int row = row0 + r;
    float4 v = make_float4(0.f, 0.f, 0.f, 0.f);
    if (row < N) v = reinterpret_cast<const float4*>(X + (size_t)row * K)[k >> 2];
    *reinterpret_cast<float4*>(&xs[r][k]) = v;
  }
  __syncthreads();

  constexpr int TC = COLS / 4;
  const int tc = t % TC, tr = t / TC;
  const int c0 = tc * 4, r0 = tr * 4;
  float acc[4][4] = {{0.f}};

  for (int k = 0; k < K; k += 4) {
    float4 a[4], b[4];
#pragma unroll
    for (int i = 0; i < 4; ++i)
      a[i] = *reinterpret_cast<const float4*>(&xs[r0 + i][k]);
#pragma unroll
    for (int j = 0; j < 4; ++j)
      b[j] = *reinterpret_cast<const float4*>(&ws[k + j][c0]);
#pragma unroll
    for (int i = 0; i < 4; ++i) {
      acc[i][0] = fmaf(a[i].x, b[0].x, acc[i][0]);
      acc[i][1] = fmaf(a[i].x, b[0].y, acc[i][1]);
      acc[i][2] = fmaf(a[i].x, b[0].z, acc[i][2]);
      acc[i][3] = fmaf(a[i].x, b[0].w, acc[i][3]);
      acc[i][0] = fmaf(a[i].y, b[1].x, acc[i][0]);
      acc[i][1] = fmaf(a[i].y, b[1].y, acc[i][1]);
      acc[i][2] = fmaf(a[i].y, b[1].z, acc[i][2]);
      acc[i][3] = fmaf(a[i].y, b[1].w, acc[i][3]);
      acc[i][0] = fmaf(a[i].z, b[2].x, acc[i][0]);
      acc[i][1] = fmaf(a[i].z, b[2].y, acc[i][1]);
      acc[i][2] = fmaf(a[i].z, b[2].z, acc[i][2]);
      acc[i][3] = fmaf(a[i].z, b[2].w, acc[i][3]);
      acc[i][0] = fmaf(a[i].w, b[3].x, acc[i][0]);
      acc[i][1] = fmaf(a[i].w, b[3].y, acc[i][1]);
      acc[i][2] = fmaf(a[i].w, b[3].z, acc[i][2]);
      acc[i][3] = fmaf(a[i].w, b[3].w, acc[i][3]);
    }
  }

#pragma unroll
  for (int i = 0; i < 4; ++i) {
    int row = row0 + r0 + i;
    if (row < N) {
      float di = dinv[row];
      __half2 p01 = __floats2half2_rn(acc[i][0] * di, acc[i][1] * di);
      __half2 p23 = __floats2half2_rn(acc[i][2] * di, acc[i][3] * di);
      union { __half2 h2[2]; uint2 u; } cvt;
      cvt.h2[0] = p01; cvt.h2[1] = p23;
      *reinterpret_cast<uint2*>(O + (size_t)row * COLS + c0) = cvt.u;
    }
  }
}

// ========== layer-2 GEMM (scalar-A form; K=64, COLS=32) ==========

template <int ROWS, int COLS, int K>
__global__ __launch_bounds__(256) void gemm_kernel(const float* __restrict__ X,
                                                   const float* __restrict__ W,
                                                   const float* __restrict__ dinv,
                                                   __half* __restrict__ O, int N) {
  __shared__ float xs[ROWS][K + 4];
  __shared__ float ws[K][COLS];
  const int t = threadIdx.x;
  const int row0 = blockIdx.x * ROWS;

  constexpr int WV = K * COLS / 4;
  for (int i = t; i < WV; i += 256) {
    float4 v = reinterpret_cast<const float4*>(W)[i];
    int base = i * 4;
    int k = base / COLS, c = base % COLS;
    ws[k][c] = v.x; ws[k][c + 1] = v.y; ws[k][c + 2] = v.z; ws[k][c + 3] = v.w;
  }
  constexpr int XV = ROWS * K / 4;
  for (int i = t; i < XV; i += 256) {
    int base = i * 4;
    int r = base / K, k = base % K;
    int row = row0 + r;
    float4 v = make_float4(0.f, 0.f, 0.f, 0.f);
    if (row < N) v = reinterpret_cast<const float4*>(X + (size_t)row * K)[k >> 2];
    *reinterpret_cast<float4*>(&xs[r][k]) = v;
  }
  __syncthreads();

  constexpr int TC = COLS / 4;
  const int tc = t % TC, tr = t / TC;
  const int c0 = tc * 4, r0 = tr * 4;
  float acc[4][4] = {{0.f}};

#pragma unroll 8
  for (int k = 0; k < K; ++k) {
    float a0 = xs[r0 + 0][k];
    float a1 = xs[r0 + 1][k];
    float a2 = xs[r0 + 2][k];
    float a3 = xs[r0 + 3][k];
    float4 b = *reinterpret_cast<const float4*>(&ws[k][c0]);
    acc[0][0] = fmaf(a0, b.x, acc[0][0]); acc[0][1] = fmaf(a0, b.y, acc[0][1]);
    acc[0][2] = fmaf(a0, b.z, acc[0][2]); acc[0][3] = fmaf(a0, b.w, acc[0][3]);
    acc[1][0] = fmaf(a1, b.x, acc[1][0]); acc[1][1] = fmaf(a1, b.y, acc[1][1]);
    acc[1][2] = fmaf(a1, b.z, acc[1][2]); acc[1][3] = fmaf(a1, b.w, acc[1][3]);
    acc[2][0] = fmaf(a2, b.x, acc[2][0]); acc[2][1] = fmaf(a2, b.y, acc[2][1]);
    acc[2][2] = fmaf(a2, b.z, acc[2][2]); acc[2][3] = fmaf(a2, b.w, acc[2][3]);
    acc[3][0] = fmaf(a3, b.x, acc[3][0]); acc[3][1] = fmaf(a3, b.y, acc[3][1]);
    acc[3][2] = fmaf(a3, b.z, acc[3][2]); acc[3][3] = fmaf(a3, b.w, acc[3][3]);
  }

#pragma unroll
  for (int i = 0; i < 4; ++i) {
    int row = row0 + r0 + i;
    if (row < N) {
      float di = dinv[row];
      __half2 p01 = __floats2half2_rn(acc[i][0] * di, acc[i][1] * di);
      __half2 p23 = __floats2half2_rn(acc[i][2] * di, acc[i][3] * di);
      union { __half2 h2[2]; uint2 u; } cvt;
      cvt.h2[0] = p01; cvt.h2[1] = p23;
      *reinterpret_cast<uint2*>(O + (size_t)row * COLS + c0) = cvt.u;
    }
  }
}

// ================= CSR gather aggregation (fused epilogue) =================
// Sub-wave per node: each lane owns fixed columns; no cross-lane reduction.
// 8-deep predicated unroll keeps 8 independent row loads in flight per sub-wave.

// FDIM=64: 16 lanes/node, lane = 4 columns (uint2 = 4 halves).
__global__ __launch_bounds__(256) void gather64_kernel(const int* __restrict__ rowptr,
                                                       const int* __restrict__ ssrc,
                                                       const float* __restrict__ dinv,
                                                       const uint2* __restrict__ g,
                                                       const float4* __restrict__ bias,
                                                       float4* __restrict__ outb, int N) {
  int node = (blockIdx.x * 256 + threadIdx.x) >> 4;
  int col = threadIdx.x & 15;
  if (node >= N) return;
  int beg = rowptr[node], end = rowptr[node + 1];
  float4 a0 = {0.f, 0.f, 0.f, 0.f}, a1 = a0;
  for (int i = beg; i < end; i += 8) {
    int cnt = end - i;
    uint2 v[8];
#pragma unroll
    for (int u = 0; u < 8; ++u) {
      if (u < cnt) {
        int s = ssrc[i + u];
        v[u] = g[(size_t)s * 16 + col];
      }
    }
#pragma unroll
    for (int u = 0; u < 8; ++u) {
      if (u < cnt) {
        float2 f0 = __half22float2(*(__half2*)&v[u].x);
        float2 f1 = __half22float2(*(__half2*)&v[u].y);
        if (u & 1) { a1.x += f0.x; a1.y += f0.y; a1.z += f1.x; a1.w += f1.y; }
        else       { a0.x += f0.x; a0.y += f0.y; a0.z += f1.x; a0.w += f1.y; }
      }
    }
  }
  uint2 vs = g[(size_t)node * 16 + col];
  float2 g01 = __half22float2(*(__half2*)&vs.x);
  float2 g23 = __half22float2(*(__half2*)&vs.y);
  float di = dinv[node];
  float4 bb = bias[col];
  float4 o;
  o.x = fmaxf(fmaf(di, (a0.x + a1.x) + g01.x, bb.x), 0.f);
  o.y = fmaxf(fmaf(di, (a0.y + a1.y) + g01.y, bb.y), 0.f);
  o.z = fmaxf(fmaf(di, (a0.z + a1.z) + g23.x, bb.z), 0.f);
  o.w = fmaxf(fmaf(di, (a0.w + a1.w) + g23.y, bb.w), 0.f);
  outb[(size_t)node * 16 + col] = o;
}

// FDIM=32: 8 lanes/node, lane = 4 columns (uint2 = 4 halves). No relu.
__global__ __launch_bounds__(256) void gather32_kernel(const int* __restrict__ rowptr,
                                                       const int* __restrict__ ssrc,
                                                       const float* __restrict__ dinv,
                                                       const uint2* __restrict__ g,
                                                       const float4* __restrict__ bias,
                                                       float4* __restrict__ outb, int N) {
  int node = (blockIdx.x * 256 + threadIdx.x) >> 3;
  int col = threadIdx.x & 7;
  if (node >= N) return;
  int beg = rowptr[node], end = rowptr[node + 1];
  float4 a0 = {0.f, 0.f, 0.f, 0.f}, a1 = a0;
  for (int i = beg; i < end; i += 8) {
    int cnt = end - i;
    uint2 v[8];
#pragma unroll
    for (int u = 0; u < 8; ++u) {
      if (u < cnt) {
        int s = ssrc[i + u];
        v[u] = g[(size_t)s * 8 + col];
      }
    }
#pragma unroll
    for (int u = 0; u < 8; ++u) {
      if (u < cnt) {
        float2 f0 = __half22float2(*(__half2*)&v[u].x);
        float2 f1 = __half22float2(*(__half2*)&v[u].y);
        if (u & 1) { a1.x += f0.x; a1.y += f0.y; a1.z += f1.x; a1.w += f1.y; }
        else       { a0.x += f0.x; a0.y += f0.y; a0.z += f1.x; a0.w += f1.y; }
      }
    }
  }
  uint2 vs = g[(size_t)node * 8 + col];
  float2 g01 = __half22float2(*(__half2*)&vs.x);
  float2 g23 = __half22float2(*(__half2*)&vs.y);
  float di = dinv[node];
  float4 bb = bias[col];
  float4 o;
  o.x = fmaf(di, (a0.x + a1.x) + g01.x, bb.x);
  o.y = fmaf(di, (a0.y + a1.y) + g01.y, bb.y);
  o.z = fmaf(di, (a0.z + a1.z) + g23.x, bb.z);
  o.w = fmaf(di, (a0.w + a1.w) + g23.y, bb.w);
  outb[(size_t)node * 8 + col] = o;
}

// ================= launch =================

extern "C" void kernel_launch(void* const* d_in, const int* in_sizes, int n_in,
                              void* d_out, int out_size, void* d_ws, size_t ws_size,
                              hipStream_t stream) {
  const float* x  = (const float*)d_in[0];
  const int*   ei = (const int*)d_in[1];
  const float* W1 = (const float*)d_in[2];
  const float* b1 = (const float*)d_in[3];
  const float* W2 = (const float*)d_in[4];
  const float* b2 = (const float*)d_in[5];
  float* out = (float*)d_out;

  const int H = in_sizes[3];            // 64
  const int F = in_sizes[2] / H;        // 128
  const int N = in_sizes[0] / F;        // 100000
  const int E = in_sizes[1] / 2;        // 1600000
  const int* src = ei;
  const int* dst = ei + E;
  const int NB = (N + 511) >> SHIFT;    // coarse buckets (196 for N=100k)

  char* w = (char*)d_ws;
  auto alloc = [&](size_t bytes) { char* p = w; w += (bytes + 255) & ~(size_t)255; return p; };
  int*    histT    = (int*)alloc((size_t)256 * B_HIST * 4);
  int*    bsum     = (int*)alloc(256 * 4);
  int*    colstart = (int*)alloc(257 * 4);
  int*    pbuf     = (int*)alloc((size_t)E * 4);
  int*    ssrc     = (int*)alloc((size_t)E * 4);
  int*    rowptr   = (int*)alloc((size_t)(N + 1) * 4);
  float*  dinv     = (float*)alloc((size_t)N * 4);
  __half* g1       = (__half*)alloc((size_t)N * 64 * 2);
  float*  buf1     = (float*)alloc((size_t)N * 64 * 4);
  __half* g2       = (__half*)alloc((size_t)N * 32 * 2);

  // CSR build (no global atomics)
  p1_hist<<<B_HIST, 256, 0, stream>>>(dst, histT, E);
  p2a_colscan<<<256, 256, 0, stream>>>(histT, bsum);
  p2b_scan<<<1, 256, 0, stream>>>(bsum, colstart);
  p3_scatter<<<B_HIST, 256, 0, stream>>>(src, dst, histT, colstart, pbuf, E);
  p4_fine<<<NB, 256, 0, stream>>>(pbuf, colstart, rowptr, dinv, ssrc, N, NB);

  // layer 1: g1 = dinv .* (x @ W1)   (fp16)
  gemmk4_kernel<64, 64, 128><<<(N + 63) / 64, 256, 0, stream>>>(x, W1, dinv, g1, N);
  gather64_kernel<<<(N * 16 + 255) / 256, 256, 0, stream>>>(rowptr, ssrc, dinv,
      (const uint2*)g1, (const float4*)b1, (float4*)buf1, N);

  // layer 2: g2 = dinv .* (r1 @ W2)  (fp16)
  gemm_kernel<128, 32, 64><<<(N + 127) / 128, 256, 0, stream>>>(buf1, W2, dinv, g2, N);
  gather32_kernel<<<(N * 8 + 255) / 256, 256, 0, stream>>>(rowptr, ssrc, dinv,
      (const uint2*)g2, (const float4*)b2, (float4*)out, N);
}

// Round 8
// 144.752 us; speedup vs baseline: 14.5467x; 1.1885x over previous
//
#include <hip/hip_runtime.h>
#include <hip/hip_fp16.h>

#define B_HIST 512   // blocks in hist/scatter phases (must match both)
#define SHIFT  9     // coarse bucket = dst >> 9 (512 nodes/bucket); NB <= 256 for N <= 131072

typedef _Float16 f16x8 __attribute__((ext_vector_type(8)));
typedef float f32x4 __attribute__((ext_vector_type(4)));

// ================= CSR build: two-level counting sort, LDS atomics only =================

__global__ __launch_bounds__(256) void p1_hist(const int* __restrict__ dst,
                                               int* __restrict__ histT, int E) {
  __shared__ int h[256];
  const int t = threadIdx.x;
  h[t] = 0;
  __syncthreads();
  const int epb = (E + B_HIST - 1) / B_HIST;
  const int beg = blockIdx.x * epb;
  const int end = min(beg + epb, E);
  for (int e = beg + t; e < end; e += 256)
    atomicAdd(&h[dst[e] >> SHIFT], 1);          // LDS atomic
  __syncthreads();
  histT[t * B_HIST + blockIdx.x] = h[t];
}

__global__ __launch_bounds__(256) void p2a_colscan(int* __restrict__ histT,
                                                   int* __restrict__ bsum) {
  __shared__ int sdata[256];
  const int bin = blockIdx.x, t = threadIdx.x;
  const int i0 = bin * B_HIST + 2 * t;
  int c0 = histT[i0], c1 = histT[i0 + 1];
  int s = c0 + c1;
  sdata[t] = s;
  __syncthreads();
  for (int off = 1; off < 256; off <<= 1) {
    int x = 0;
    if (t >= off) x = sdata[t - off];
    __syncthreads();
    if (t >= off) sdata[t] += x;
    __syncthreads();
  }
  int excl = sdata[t] - s;
  histT[i0] = excl;
  histT[i0 + 1] = excl + c0;
  if (t == 255) bsum[bin] = sdata[255];
}

__global__ __launch_bounds__(256) void p2b_scan(const int* __restrict__ bsum,
                                                int* __restrict__ colstart) {
  __shared__ int sdata[256];
  const int t = threadIdx.x;
  int v = bsum[t];
  sdata[t] = v;
  __syncthreads();
  for (int off = 1; off < 256; off <<= 1) {
    int x = 0;
    if (t >= off) x = sdata[t - off];
    __syncthreads();
    if (t >= off) sdata[t] += x;
    __syncthreads();
  }
  colstart[t] = sdata[t] - v;
  if (t == 255) colstart[256] = sdata[255];
}

__global__ __launch_bounds__(256) void p3_scatter(const int* __restrict__ src,
                                                  const int* __restrict__ dst,
                                                  const int* __restrict__ histT,
                                                  const int* __restrict__ colstart,
                                                  int* __restrict__ pbuf, int E) {
  __shared__ int cur[256];
  const int t = threadIdx.x;
  cur[t] = colstart[t] + histT[t * B_HIST + blockIdx.x];
  __syncthreads();
  const int epb = (E + B_HIST - 1) / B_HIST;
  const int beg = blockIdx.x * epb;
  const int end = min(beg + epb, E);
  for (int e = beg + t; e < end; e += 256) {
    int d = dst[e];
    int s = src[e];
    int pos = atomicAdd(&cur[d >> SHIFT], 1);   // LDS atomic
    pbuf[pos] = ((d & 511) << 17) | s;
  }
}

__global__ __launch_bounds__(256) void p4_fine(const int* __restrict__ pbuf,
                                               const int* __restrict__ colstart,
                                               int* __restrict__ rowptr,
                                               float* __restrict__ dinv,
                                               int* __restrict__ ssrc, int N, int NB) {
  __shared__ int cnt[512];
  __shared__ int sdata[256];
  __shared__ int cur[512];
  const int b = blockIdx.x, t = threadIdx.x;
  const int base = colstart[b], endp = colstart[b + 1];
  cnt[2 * t] = 0; cnt[2 * t + 1] = 0;
  __syncthreads();
  for (int i = base + t; i < endp; i += 256)
    atomicAdd(&cnt[pbuf[i] >> 17], 1);
  __syncthreads();
  int c0 = cnt[2 * t], c1 = cnt[2 * t + 1];
  int s = c0 + c1;
  sdata[t] = s;
  __syncthreads();
  for (int off = 1; off < 256; off <<= 1) {
    int x = 0;
    if (t >= off) x = sdata[t - off];
    __syncthreads();
    if (t >= off) sdata[t] += x;
    __syncthreads();
  }
  int excl = sdata[t] - s;
  int e0 = base + excl, e1 = base + excl + c0;
  cur[2 * t] = e0;
  cur[2 * t + 1] = e1;
  int node0 = (b << SHIFT) + 2 * t;
  if (node0 < N) {
    rowptr[node0] = e0;
    dinv[node0] = rsqrtf((float)c0 + 1.0f);
  }
  if (node0 + 1 < N) {
    rowptr[node0 + 1] = e1;
    dinv[node0 + 1] = rsqrtf((float)c1 + 1.0f);
  }
  if (b == NB - 1 && t == 0) rowptr[N] = endp;
  __syncthreads();
  for (int i = base + t; i < endp; i += 256) {
    int p = pbuf[i];
    int pos = atomicAdd(&cur[p >> 17], 1);      // LDS atomic
    ssrc[pos] = p & 0x1FFFF;
  }
}

// ========== MFMA GEMM: O[N][COLS] (fp16, *dinv) = X[N][K]fp32 @ W[K][COLS]fp32 ==========
// 256 thr = 4 waves; each wave one 16-row MFMA tile; block covers 64 rows.
// X, W converted to fp16 at staging; mfma_f32_16x16x32_f16, fp32 accumulate.
// A-frag: row=lane&15, k=(lane>>4)*8+j. B-frag: col=lane&15, same k.
// C/D: col=lane&15, row=(lane>>4)*4+r (guide-verified).

template <int COLS, int K>
__global__ __launch_bounds__(256) void mfma_gemm(const float* __restrict__ X,
                                                 const float* __restrict__ W,
                                                 const float* __restrict__ dinv,
                                                 __half* __restrict__ O, int N) {
  constexpr int NKK = K / 32;        // MFMA K-steps
  constexpr int NCT = COLS / 16;     // col tiles
  constexpr int RCH = K / 8;         // 16B fp16 chunks per row
  constexpr int SWM = RCH - 1;       // chunk swizzle mask
  __shared__ _Float16 xs[64 * K];
  __shared__ _Float16 wb[K * COLS];  // packed B-frags: ((kk*4+q)*COLS + col)*8 + j
  const int t = threadIdx.x;
  const int row0 = blockIdx.x * 64;

  // pack W fragments (tiny, L2-resident)
  for (int task = t; task < NKK * 4 * COLS; task += 256) {
    int col = task % COLS;
    int kq = task / COLS;            // kk*4+q
    _Float16 tmp[8];
#pragma unroll
    for (int j = 0; j < 8; ++j)
      tmp[j] = (_Float16)W[(kq * 8 + j) * COLS + col];
    *reinterpret_cast<f16x8*>(&wb[task * 8]) = *reinterpret_cast<const f16x8*>(tmp);
  }
  // stage X tile as fp16, chunk-XOR-swizzled
  for (int task = t; task < 64 * RCH; task += 256) {
    int row = task / RCH, c = task % RCH;
    int grow = row0 + row;
    float4 v0 = make_float4(0.f, 0.f, 0.f, 0.f), v1 = v0;
    if (grow < N) {
      const float4* xr = reinterpret_cast<const float4*>(X + (size_t)grow * K);
      v0 = xr[c * 2];
      v1 = xr[c * 2 + 1];
    }
    _Float16 tmp[8] = {(_Float16)v0.x, (_Float16)v0.y, (_Float16)v0.z, (_Float16)v0.w,
                       (_Float16)v1.x, (_Float16)v1.y, (_Float16)v1.z, (_Float16)v1.w};
    int sc = c ^ (row & SWM);
    *reinterpret_cast<f16x8*>(&xs[row * K + sc * 8]) = *reinterpret_cast<const f16x8*>(tmp);
  }
  __syncthreads();

  const int wave = t >> 6, lane = t & 63;
  const int q = lane >> 4, c = lane & 15;
  const int wrow = wave * 16;

  // preload all B fragments to registers
  f16x8 bfrag[NKK][NCT];
#pragma unroll
  for (int kk = 0; kk < NKK; ++kk)
#pragma unroll
    for (int ct = 0; ct < NCT; ++ct)
      bfrag[kk][ct] = *reinterpret_cast<const f16x8*>(
          &wb[(size_t)((kk * 4 + q) * COLS + ct * 16 + c) * 8]);

  f32x4 acc[NCT];
#pragma unroll
  for (int ct = 0; ct < NCT; ++ct) acc[ct] = {0.f, 0.f, 0.f, 0.f};

#pragma unroll
  for (int kk = 0; kk < NKK; ++kk) {
    int row = wrow + c;              // A row (block-local)
    int cc = (kk * 4 + q) ^ (row & SWM);
    f16x8 afrag = *reinterpret_cast<const f16x8*>(&xs[row * K + cc * 8]);
#pragma unroll
    for (int ct = 0; ct < NCT; ++ct)
      acc[ct] = __builtin_amdgcn_mfma_f32_16x16x32_f16(afrag, bfrag[kk][ct], acc[ct], 0, 0, 0);
  }

#pragma unroll
  for (int r = 0; r < 4; ++r) {
    int row = row0 + wrow + q * 4 + r;
    if (row < N) {
      float di = dinv[row];
#pragma unroll
      for (int ct = 0; ct < NCT; ++ct)
        O[(size_t)row * COLS + ct * 16 + c] = __float2half(acc[ct][r] * di);
    }
  }
}

// ================= CSR gather aggregation (fused epilogue) =================
// Sub-wave per node: each lane owns fixed columns; no cross-lane reduction.

// FDIM=64: 16 lanes/node, lane = 4 columns (uint2 = 4 halves).
__global__ __launch_bounds__(256) void gather64_kernel(const int* __restrict__ rowptr,
                                                       const int* __restrict__ ssrc,
                                                       const float* __restrict__ dinv,
                                                       const uint2* __restrict__ g,
                                                       const float4* __restrict__ bias,
                                                       float4* __restrict__ outb, int N) {
  int node = (blockIdx.x * 256 + threadIdx.x) >> 4;
  int col = threadIdx.x & 15;
  if (node >= N) return;
  int beg = rowptr[node], end = rowptr[node + 1];
  float4 a0 = {0.f, 0.f, 0.f, 0.f}, a1 = a0;
  for (int i = beg; i < end; i += 8) {
    int cnt = end - i;
    uint2 v[8];
#pragma unroll
    for (int u = 0; u < 8; ++u) {
      if (u < cnt) {
        int s = ssrc[i + u];
        v[u] = g[(size_t)s * 16 + col];
      }
    }
#pragma unroll
    for (int u = 0; u < 8; ++u) {
      if (u < cnt) {
        float2 f0 = __half22float2(*(__half2*)&v[u].x);
        float2 f1 = __half22float2(*(__half2*)&v[u].y);
        if (u & 1) { a1.x += f0.x; a1.y += f0.y; a1.z += f1.x; a1.w += f1.y; }
        else       { a0.x += f0.x; a0.y += f0.y; a0.z += f1.x; a0.w += f1.y; }
      }
    }
  }
  uint2 vs = g[(size_t)node * 16 + col];
  float2 g01 = __half22float2(*(__half2*)&vs.x);
  float2 g23 = __half22float2(*(__half2*)&vs.y);
  float di = dinv[node];
  float4 bb = bias[col];
  float4 o;
  o.x = fmaxf(fmaf(di, (a0.x + a1.x) + g01.x, bb.x), 0.f);
  o.y = fmaxf(fmaf(di, (a0.y + a1.y) + g01.y, bb.y), 0.f);
  o.z = fmaxf(fmaf(di, (a0.z + a1.z) + g23.x, bb.z), 0.f);
  o.w = fmaxf(fmaf(di, (a0.w + a1.w) + g23.y, bb.w), 0.f);
  outb[(size_t)node * 16 + col] = o;
}

// FDIM=32: 8 lanes/node, lane = 4 columns (uint2 = 4 halves). No relu.
__global__ __launch_bounds__(256) void gather32_kernel(const int* __restrict__ rowptr,
                                                       const int* __restrict__ ssrc,
                                                       const float* __restrict__ dinv,
                                                       const uint2* __restrict__ g,
                                                       const float4* __restrict__ bias,
                                                       float4* __restrict__ outb, int N) {
  int node = (blockIdx.x * 256 + threadIdx.x) >> 3;
  int col = threadIdx.x & 7;
  if (node >= N) return;
  int beg = rowptr[node], end = rowptr[node + 1];
  float4 a0 = {0.f, 0.f, 0.f, 0.f}, a1 = a0;
  for (int i = beg; i < end; i += 8) {
    int cnt = end - i;
    uint2 v[8];
#pragma unroll
    for (int u = 0; u < 8; ++u) {
      if (u < cnt) {
        int s = ssrc[i + u];
        v[u] = g[(size_t)s * 8 + col];
      }
    }
#pragma unroll
    for (int u = 0; u < 8; ++u) {
      if (u < cnt) {
        float2 f0 = __half22float2(*(__half2*)&v[u].x);
        float2 f1 = __half22float2(*(__half2*)&v[u].y);
        if (u & 1) { a1.x += f0.x; a1.y += f0.y; a1.z += f1.x; a1.w += f1.y; }
        else       { a0.x += f0.x; a0.y += f0.y; a0.z += f1.x; a0.w += f1.y; }
      }
    }
  }
  uint2 vs = g[(size_t)node * 8 + col];
  float2 g01 = __half22float2(*(__half2*)&vs.x);
  float2 g23 = __half22float2(*(__half2*)&vs.y);
  float di = dinv[node];
  float4 bb = bias[col];
  float4 o;
  o.x = fmaf(di, (a0.x + a1.x) + g01.x, bb.x);
  o.y = fmaf(di, (a0.y + a1.y) + g01.y, bb.y);
  o.z = fmaf(di, (a0.z + a1.z) + g23.x, bb.z);
  o.w = fmaf(di, (a0.w + a1.w) + g23.y, bb.w);
  outb[(size_t)node * 8 + col] = o;
}

// ================= launch =================

extern "C" void kernel_launch(void* const* d_in, const int* in_sizes, int n_in,
                              void* d_out, int out_size, void* d_ws, size_t ws_size,
                              hipStream_t stream) {
  const float* x  = (const float*)d_in[0];
  const int*   ei = (const int*)d_in[1];
  const float* W1 = (const float*)d_in[2];
  const float* b1 = (const float*)d_in[3];
  const float* W2 = (const float*)d_in[4];
  const float* b2 = (const float*)d_in[5];
  float* out = (float*)d_out;

  const int H = in_sizes[3];            // 64
  const int F = in_sizes[2] / H;        // 128
  const int N = in_sizes[0] / F;        // 100000
  const int E = in_sizes[1] / 2;        // 1600000
  const int* src = ei;
  const int* dst = ei + E;
  const int NB = (N + 511) >> SHIFT;    // coarse buckets (196 for N=100k)

  char* w = (char*)d_ws;
  auto alloc = [&](size_t bytes) { char* p = w; w += (bytes + 255) & ~(size_t)255; return p; };
  int*    histT    = (int*)alloc((size_t)256 * B_HIST * 4);
  int*    bsum     = (int*)alloc(256 * 4);
  int*    colstart = (int*)alloc(257 * 4);
  int*    pbuf     = (int*)alloc((size_t)E * 4);
  int*    ssrc     = (int*)alloc((size_t)E * 4);
  int*    rowptr   = (int*)alloc((size_t)(N + 1) * 4);
  float*  dinv     = (float*)alloc((size_t)N * 4);
  __half* g1       = (__half*)alloc((size_t)N * 64 * 2);
  float*  buf1     = (float*)alloc((size_t)N * 64 * 4);
  __half* g2       = (__half*)alloc((size_t)N * 32 * 2);

  // CSR build (no global atomics)
  p1_hist<<<B_HIST, 256, 0, stream>>>(dst, histT, E);
  p2a_colscan<<<256, 256, 0, stream>>>(histT, bsum);
  p2b_scan<<<1, 256, 0, stream>>>(bsum, colstart);
  p3_scatter<<<B_HIST, 256, 0, stream>>>(src, dst, histT, colstart, pbuf, E);
  p4_fine<<<NB, 256, 0, stream>>>(pbuf, colstart, rowptr, dinv, ssrc, N, NB);

  // layer 1: g1 = dinv .* (x @ W1)   (fp16, MFMA)
  mfma_gemm<64, 128><<<(N + 63) / 64, 256, 0, stream>>>(x, W1, dinv, g1, N);
  gather64_kernel<<<(N * 16 + 255) / 256, 256, 0, stream>>>(rowptr, ssrc, dinv,
      (const uint2*)g1, (const float4*)b1, (float4*)buf1, N);

  // layer 2: g2 = dinv .* (r1 @ W2)  (fp16, MFMA)
  mfma_gemm<32, 64><<<(N + 63) / 64, 256, 0, stream>>>(buf1, W2, dinv, g2, N);
  gather32_kernel<<<(N * 8 + 255) / 256, 256, 0, stream>>>(rowptr, ssrc, dinv,
      (const uint2*)g2, (const float4*)b2, (float4*)out, N);
}